// Round 3
// baseline (846.657 us; speedup 1.0000x reference)
//
#include <hip/hip_runtime.h>
#include <hip/hip_bf16.h>

#define N_NODES  100000
#define N_EDGES  1600000
#define N_GRAPHS 2000
#define N_FEAT   13
#define HID      128
#define NB       ((N_NODES + 127) / 128)   // 782 buckets of 128 nodes
#define BCAP     2560                       // avg 2046 edges/bucket, >11 sigma headroom

// -------------------- dinv --------------------
__global__ void k_dinv(const int* __restrict__ indeg, float* __restrict__ dinv, int n) {
    int i = blockIdx.x * 256 + threadIdx.x;
    if (i < n) dinv[i] = rsqrtf((float)(indeg[i] + 1));   // +1 self loop
}

// -------------------- bucketed topology build --------------------
// phase A: append (src<<7 | dstLocal) into per-bucket arrays
__global__ void k_bucket(const int* __restrict__ src, const int* __restrict__ dst,
                         int* __restrict__ bcur, unsigned int* __restrict__ bstore, int E) {
    int e = blockIdx.x * 256 + threadIdx.x;
    if (e < E) {
        int d = dst[e];
        int b = d >> 7;
        int pos = atomicAdd(&bcur[b], 1);
        if (pos < BCAP)
            bstore[(size_t)b * BCAP + pos] = ((unsigned int)src[e] << 7) | (unsigned int)(d & 127);
    }
}

// phase B1: per-bucket LDS histogram -> indeg (coalesced, no global atomics)
__global__ void k_bhist(const unsigned int* __restrict__ bstore, const int* __restrict__ bcur,
                        int* __restrict__ indeg, int n) {
    __shared__ int cnt[128];
    int b = blockIdx.x, t = threadIdx.x;
    if (t < 128) cnt[t] = 0;
    __syncthreads();
    int c = min(bcur[b], BCAP);
    for (int i = t; i < c; i += 256) atomicAdd(&cnt[bstore[(size_t)b * BCAP + i] & 127], 1);
    __syncthreads();
    int node = b * 128 + t;
    if (t < 128 && node < n) indeg[node] = cnt[t];
}

// phase B2: per-bucket CSR fill; writes land in one contiguous ~8KB csr window
__global__ void k_bfill(const unsigned int* __restrict__ bstore, const int* __restrict__ bcur,
                        const int* __restrict__ off, int* __restrict__ csr, int n) {
    __shared__ int cur[128];
    __shared__ int loff[128];
    int b = blockIdx.x, t = threadIdx.x;
    if (t < 128) {
        cur[t] = 0;
        int node = b * 128 + t;
        loff[t] = (node < n) ? off[node] : 0;
    }
    __syncthreads();
    int c = min(bcur[b], BCAP);
    for (int i = t; i < c; i += 256) {
        unsigned int e = bstore[(size_t)b * BCAP + i];
        int dl = e & 127;
        int s = (int)(e >> 7);
        int p = loff[dl] + atomicAdd(&cur[dl], 1);
        csr[p] = s;
    }
}

// -------------------- scans (exclusive) --------------------
__global__ void k_scan1(const int* __restrict__ in, int* __restrict__ out,
                        int* __restrict__ bsum, int n) {
    __shared__ int ts[256];
    int t = threadIdx.x;
    int base = blockIdx.x * 1024 + t * 4;
    int v0 = (base + 0 < n) ? in[base + 0] : 0;
    int v1 = (base + 1 < n) ? in[base + 1] : 0;
    int v2 = (base + 2 < n) ? in[base + 2] : 0;
    int v3 = (base + 3 < n) ? in[base + 3] : 0;
    int s = v0 + v1 + v2 + v3;
    ts[t] = s;
    __syncthreads();
    for (int o = 1; o < 256; o <<= 1) {
        int x = (t >= o) ? ts[t - o] : 0;
        __syncthreads();
        ts[t] += x;
        __syncthreads();
    }
    if (t == 255) bsum[blockIdx.x] = ts[255];
    int run = ts[t] - s;
    if (base + 0 < n) out[base + 0] = run; run += v0;
    if (base + 1 < n) out[base + 1] = run; run += v1;
    if (base + 2 < n) out[base + 2] = run; run += v2;
    if (base + 3 < n) out[base + 3] = run;
}

__global__ void k_scan_block(const int* __restrict__ in, int* __restrict__ out, int len) {
    __shared__ int ts[256];
    int t = threadIdx.x;
    int v[8];
    int s = 0;
#pragma unroll
    for (int j = 0; j < 8; j++) {
        int i = t * 8 + j;
        v[j] = (i < len) ? in[i] : 0;
        s += v[j];
    }
    ts[t] = s;
    __syncthreads();
    for (int o = 1; o < 256; o <<= 1) {
        int x = (t >= o) ? ts[t - o] : 0;
        __syncthreads();
        ts[t] += x;
        __syncthreads();
    }
    int run = ts[t] - s;
#pragma unroll
    for (int j = 0; j < 8; j++) {
        int i = t * 8 + j;
        if (i < len) out[i] = run;
        run += v[j];
    }
}

__global__ void k_scan3(int* __restrict__ out, const int* __restrict__ bpre, int n) {
    int i = blockIdx.x * 256 + threadIdx.x;
    if (i < n) out[i] += bpre[i >> 10];
}

// -------------------- layer 0: xs = dinv * x, padded to 16 cols --------------------
__global__ void k_scale_pad(const float* __restrict__ x, const float* __restrict__ dinv,
                            float* __restrict__ xs, int n) {
    int i = blockIdx.x * 256 + threadIdx.x;
    if (i >= n) return;
    float dv = dinv[i];
    float r[16];
#pragma unroll
    for (int k = 0; k < N_FEAT; k++) r[k] = dv * x[i * N_FEAT + k];
    r[13] = r[14] = r[15] = 0.f;
    float4* o = (float4*)&xs[i * 16];
    o[0] = float4{r[0], r[1], r[2], r[3]};
    o[1] = float4{r[4], r[5], r[6], r[7]};
    o[2] = float4{r[8], r[9], r[10], r[11]};
    o[3] = float4{r[12], r[13], r[14], r[15]};
}

// -------------------- layer 0 gather on 16-wide rows (quarter-wave per dst) ----------
__global__ void k_gather13(const float* __restrict__ xs, const int* __restrict__ off,
                           const int* __restrict__ indeg, const int* __restrict__ csr,
                           const float* __restrict__ dinv, float* __restrict__ agg, int n) {
    int lane = threadIdx.x & 63;
    int q = lane >> 4, l4 = lane & 15;
    int d = blockIdx.x * 16 + (threadIdx.x >> 6) * 4 + q;
    if (d >= n) return;
    int s0 = off[d], c = indeg[d];
    float acc = xs[(size_t)d * 16 + l4];   // self term (already dinv[d]-scaled)
    int p = 0;
    for (; p + 3 < c; p += 4) {
        int sa = csr[s0 + p], sb = csr[s0 + p + 1];
        int sc_ = csr[s0 + p + 2], sd_ = csr[s0 + p + 3];
        float va = xs[(size_t)sa * 16 + l4];
        float vb = xs[(size_t)sb * 16 + l4];
        float vc = xs[(size_t)sc_ * 16 + l4];
        float vd = xs[(size_t)sd_ * 16 + l4];
        acc += (va + vb) + (vc + vd);
    }
    for (; p < c; p++) acc += xs[(size_t)csr[s0 + p] * 16 + l4];
    agg[(size_t)d * 16 + l4] = dinv[d] * acc;
}

// -------------------- layer 0 GEMM: h0 = relu(agg @ W0 + b0), K=13 --------------------
__global__ void k_gemm13(const float* __restrict__ agg, const float* __restrict__ W,
                         const float* __restrict__ b, float* __restrict__ h, int n) {
    __shared__ float Ws[N_FEAT * HID];
    for (int i = threadIdx.x; i < N_FEAT * HID; i += 256) Ws[i] = W[i];
    __syncthreads();
    int i = blockIdx.x * 2 + (threadIdx.x >> 7);
    int f = threadIdx.x & 127;
    if (i >= n) return;
    float acc = b[f];
#pragma unroll
    for (int k = 0; k < N_FEAT; k++) acc += agg[(size_t)i * 16 + k] * Ws[k * HID + f];
    h[(size_t)i * HID + f] = fmaxf(acc, 0.f);
}

// -------------------- fp32 -> bf16 RTNE --------------------
__device__ __forceinline__ unsigned short f2bf(float f) {
    unsigned int b = __float_as_uint(f);
    b += 0x7fffu + ((b >> 16) & 1u);
    return (unsigned short)(b >> 16);
}

// -------------------- GEMM 128x128: ubf = bf16( dinv * (X @ W) ) --------------------
__global__ __launch_bounds__(256) void k_gemm128(const float* __restrict__ X,
                                                 const float* __restrict__ W,
                                                 const float* __restrict__ dinv,
                                                 unsigned short* __restrict__ ubf, int n) {
    __shared__ float Ws[HID * HID];   // 64 KB
    __shared__ float Xs[32 * HID];    // 16 KB
    int t = threadIdx.x;
    {
        const float4* W4 = (const float4*)W;
        float4* Ws4 = (float4*)Ws;
#pragma unroll
        for (int i = 0; i < 16; i++) Ws4[t + 256 * i] = W4[t + 256 * i];
    }
    int nb = blockIdx.x * 32;
    {
        const float4* X4 = (const float4*)X;
        float4* Xs4 = (float4*)Xs;
#pragma unroll
        for (int i = 0; i < 4; i++) {
            int idx = t + 256 * i;
            int node = idx >> 5, c4 = idx & 31;
            int g = nb + node;
            Xs4[idx] = (g < n) ? X4[(size_t)g * 32 + c4] : float4{0.f, 0.f, 0.f, 0.f};
        }
    }
    __syncthreads();

    int fg = (t & 31) * 4;
    int nl = (t >> 5) * 4;
    float acc[4][4];
#pragma unroll
    for (int j = 0; j < 4; j++)
#pragma unroll
        for (int q = 0; q < 4; q++) acc[j][q] = 0.f;

#pragma unroll 8
    for (int k = 0; k < HID; k++) {
        float4 w = *(const float4*)&Ws[k * HID + fg];
#pragma unroll
        for (int j = 0; j < 4; j++) {
            float xv = Xs[(nl + j) * HID + k];
            acc[j][0] += xv * w.x;
            acc[j][1] += xv * w.y;
            acc[j][2] += xv * w.z;
            acc[j][3] += xv * w.w;
        }
    }
#pragma unroll
    for (int j = 0; j < 4; j++) {
        int g = nb + nl + j;
        if (g < n) {
            float dv = dinv[g];
            ushort4 r;
            r.x = f2bf(dv * acc[j][0]);
            r.y = f2bf(dv * acc[j][1]);
            r.z = f2bf(dv * acc[j][2]);
            r.w = f2bf(dv * acc[j][3]);
            *(ushort4*)&ubf[(size_t)g * HID + fg] = r;
        }
    }
}

// ---- gather over bf16 rows: y = relu?( dinv[d]*(sum_nbrs + self) + b ), fp32 out ----
__global__ void k_gather128(const unsigned int* __restrict__ ubf, const int* __restrict__ off,
                            const int* __restrict__ indeg, const int* __restrict__ csr,
                            const float* __restrict__ dinv, const float* __restrict__ bias,
                            float* __restrict__ y, int n, int relu) {
    int wv = threadIdx.x >> 6;
    int lane = threadIdx.x & 63;
    int d = blockIdx.x * 4 + wv;
    if (d >= n) return;
    int half = lane >> 5, l2 = lane & 31;
    int s0 = off[d], c = indeg[d];
    const uint2* U = (const uint2*)ubf;   // one row = 32 uint2 (128 bf16)
    float a0 = 0.f, a1 = 0.f, a2 = 0.f, a3 = 0.f;

    int p = half;
    for (; p + 2 < c; p += 4) {
        int sa = csr[s0 + p], sb = csr[s0 + p + 2];
        uint2 va = U[(size_t)sa * 32 + l2];
        uint2 vb = U[(size_t)sb * 32 + l2];
        a0 += __uint_as_float(va.x << 16) + __uint_as_float(vb.x << 16);
        a1 += __uint_as_float(va.x & 0xffff0000u) + __uint_as_float(vb.x & 0xffff0000u);
        a2 += __uint_as_float(va.y << 16) + __uint_as_float(vb.y << 16);
        a3 += __uint_as_float(va.y & 0xffff0000u) + __uint_as_float(vb.y & 0xffff0000u);
    }
    for (; p < c; p += 2) {
        int s = csr[s0 + p];
        uint2 v = U[(size_t)s * 32 + l2];
        a0 += __uint_as_float(v.x << 16);
        a1 += __uint_as_float(v.x & 0xffff0000u);
        a2 += __uint_as_float(v.y << 16);
        a3 += __uint_as_float(v.y & 0xffff0000u);
    }
    if (half) {   // self term once
        uint2 v = U[(size_t)d * 32 + l2];
        a0 += __uint_as_float(v.x << 16);
        a1 += __uint_as_float(v.x & 0xffff0000u);
        a2 += __uint_as_float(v.y << 16);
        a3 += __uint_as_float(v.y & 0xffff0000u);
    }
    a0 += __shfl_xor(a0, 32);
    a1 += __shfl_xor(a1, 32);
    a2 += __shfl_xor(a2, 32);
    a3 += __shfl_xor(a3, 32);
    if (!half) {
        float dv = dinv[d];
        float4 bb = *(const float4*)&bias[l2 * 4];
        float4 r = {dv * a0 + bb.x, dv * a1 + bb.y, dv * a2 + bb.z, dv * a3 + bb.w};
        if (relu) {
            r.x = fmaxf(r.x, 0.f); r.y = fmaxf(r.y, 0.f);
            r.z = fmaxf(r.z, 0.f); r.w = fmaxf(r.w, 0.f);
        }
        *(float4*)&y[(size_t)d * HID + l2 * 4] = r;
    }
}

// -------------------- pooling --------------------
__global__ void k_cnt(const int* __restrict__ batch, int* __restrict__ cnt, int n) {
    int i = blockIdx.x * 256 + threadIdx.x;
    if (i < n) atomicAdd(&cnt[batch[i]], 1);
}

__global__ void k_pool(const float* __restrict__ h, const int* __restrict__ goff,
                       const int* __restrict__ cnt, float* __restrict__ pooledm) {
    int g = blockIdx.x;
    int t = threadIdx.x;   // 128
    int s = goff[g], c = cnt[g];
    float acc = 0.f;
    for (int i = s; i < s + c; i++) acc += h[(size_t)i * HID + t];
    pooledm[g * HID + t] = acc / (float)max(c, 1);
}

// -------------------- MLP head --------------------
__global__ void k_fc0(const float* __restrict__ in, const float* __restrict__ W,
                      const float* __restrict__ b, float* __restrict__ out) {
    __shared__ float row[128];
    int g = blockIdx.x, t = threadIdx.x;   // 256 threads
    if (t < 128) row[t] = in[g * 128 + t];
    __syncthreads();
    float acc = 0.f;
#pragma unroll 8
    for (int k = 0; k < 128; k++) acc += row[k] * W[k * 256 + t];
    acc += b[t];
    out[g * 256 + t] = fmaxf(acc, 0.f);
}

__global__ void k_fc1(const float* __restrict__ in, const float* __restrict__ W,
                      const float* __restrict__ b, float* __restrict__ out) {
    __shared__ float row[256];
    int g = blockIdx.x, t = threadIdx.x;   // 128 threads
    row[t] = in[g * 256 + t];
    row[t + 128] = in[g * 256 + t + 128];
    __syncthreads();
    float acc = 0.f;
#pragma unroll 8
    for (int k = 0; k < 256; k++) acc += row[k] * W[k * 128 + t];
    acc += b[t];
    out[g * 128 + t] = fmaxf(acc, 0.f);
}

__global__ void k_fco(const float* __restrict__ in, const float* __restrict__ Wo,
                      const float* __restrict__ bo, float* __restrict__ out) {
    int g = blockIdx.x, t = threadIdx.x;   // 64 threads = 1 wave
    float acc = in[g * 128 + t] * Wo[t] + in[g * 128 + 64 + t] * Wo[64 + t];
    for (int s = 32; s > 0; s >>= 1) acc += __shfl_down(acc, s);
    if (t == 0) out[g] = acc + bo[0];
}

// -------------------- launch --------------------
extern "C" void kernel_launch(void* const* d_in, const int* in_sizes, int n_in,
                              void* d_out, int out_size, void* d_ws, size_t ws_size,
                              hipStream_t stream) {
    const float* x   = (const float*)d_in[0];
    const int* ei    = (const int*)d_in[1];
    const int* src   = ei;
    const int* dst   = ei + N_EDGES;
    const int* batch = (const int*)d_in[2];
    const float* W0 = (const float*)d_in[3];  const float* b0 = (const float*)d_in[4];
    const float* W1 = (const float*)d_in[5];  const float* b1 = (const float*)d_in[6];
    const float* W2 = (const float*)d_in[7];  const float* b2 = (const float*)d_in[8];
    const float* Wf0 = (const float*)d_in[9];  const float* bf0 = (const float*)d_in[10];
    const float* Wf1 = (const float*)d_in[11]; const float* bf1 = (const float*)d_in[12];
    const float* Wo = (const float*)d_in[13];  const float* bo = (const float*)d_in[14];
    float* out = (float*)d_out;

    char* w = (char*)d_ws;
    size_t o = 0;
    auto take = [&](size_t bytes) -> char* {
        char* p = w + o;
        o += (bytes + 255) & ~(size_t)255;
        return p;
    };
    int* indeg    = (int*)take((size_t)N_NODES * 4);
    int* bcur     = (int*)take((size_t)NB * 4);
    int* off      = (int*)take((size_t)N_NODES * 4);
    int* bsum     = (int*)take(256 * 4);
    int* bpre     = (int*)take(256 * 4);
    int* csr      = (int*)take((size_t)N_EDGES * 4);
    float* dinv   = (float*)take((size_t)N_NODES * 4);
    int* cnt      = (int*)take((size_t)N_GRAPHS * 4);
    int* goff     = (int*)take((size_t)N_GRAPHS * 4);
    float* bufA   = (float*)take((size_t)N_NODES * HID * 4);
    float* bufB   = (float*)take((size_t)N_NODES * HID * 4);
    unsigned short* ubf = (unsigned short*)take((size_t)N_NODES * HID * 2);
    float* pooledm= (float*)take((size_t)N_GRAPHS * HID * 4);
    float* fc0    = (float*)take((size_t)N_GRAPHS * 256 * 4);
    float* fc1    = (float*)take((size_t)N_GRAPHS * HID * 4);
    // bstore (8MB) aliases ubf (25.6MB): bstore dead after k_bfill, ubf written after
    unsigned int* bstore = (unsigned int*)ubf;
    // xs/agg alias bufB (dead before first gather128 write to bufB)
    float* xs  = bufB;
    float* agg = bufB + (size_t)N_NODES * 16;

    hipMemsetAsync(bcur, 0, (size_t)NB * 4, stream);
    hipMemsetAsync(cnt, 0, (size_t)N_GRAPHS * 4, stream);

    // topology: bucket by dst, histogram -> indeg, scan -> off, bucket-local CSR fill
    k_bucket<<<(N_EDGES + 255) / 256, 256, 0, stream>>>(src, dst, bcur, bstore, N_EDGES);
    k_bhist<<<NB, 256, 0, stream>>>(bstore, bcur, indeg, N_NODES);
    k_dinv<<<(N_NODES + 255) / 256, 256, 0, stream>>>(indeg, dinv, N_NODES);
    int nb1 = (N_NODES + 1023) / 1024;
    k_scan1<<<nb1, 256, 0, stream>>>(indeg, off, bsum, N_NODES);
    k_scan_block<<<1, 256, 0, stream>>>(bsum, bpre, nb1);
    k_scan3<<<(N_NODES + 255) / 256, 256, 0, stream>>>(off, bpre, N_NODES);
    k_bfill<<<NB, 256, 0, stream>>>(bstore, bcur, off, csr, N_NODES);
    k_cnt<<<(N_NODES + 255) / 256, 256, 0, stream>>>(batch, cnt, N_NODES);
    k_scan_block<<<1, 256, 0, stream>>>(cnt, goff, N_GRAPHS);

    // layer 0: aggregate 13-wide first, then GEMM
    k_scale_pad<<<(N_NODES + 255) / 256, 256, 0, stream>>>(x, dinv, xs, N_NODES);
    k_gather13<<<(N_NODES + 15) / 16, 256, 0, stream>>>(xs, off, indeg, csr, dinv, agg, N_NODES);
    k_gemm13<<<(N_NODES + 1) / 2, 256, 0, stream>>>(agg, W0, b0, bufA, N_NODES);
    // layer 1
    k_gemm128<<<(N_NODES + 31) / 32, 256, 0, stream>>>(bufA, W1, dinv, ubf, N_NODES);
    k_gather128<<<(N_NODES + 3) / 4, 256, 0, stream>>>((const unsigned int*)ubf, off, indeg, csr, dinv, b1, bufB, N_NODES, 1);
    // layer 2 (no relu)
    k_gemm128<<<(N_NODES + 31) / 32, 256, 0, stream>>>(bufB, W2, dinv, ubf, N_NODES);
    k_gather128<<<(N_NODES + 3) / 4, 256, 0, stream>>>((const unsigned int*)ubf, off, indeg, csr, dinv, b2, bufA, N_NODES, 0);

    // pool + MLP head
    k_pool<<<N_GRAPHS, 128, 0, stream>>>(bufA, goff, cnt, pooledm);
    k_fc0<<<N_GRAPHS, 256, 0, stream>>>(pooledm, Wf0, bf0, fc0);
    k_fc1<<<N_GRAPHS, 128, 0, stream>>>(fc0, Wf1, bf1, fc1);
    k_fco<<<N_GRAPHS, 64, 0, stream>>>(fc1, Wo, bo, out);
}

// Round 5
// 571.218 us; speedup vs baseline: 1.4822x; 1.4822x over previous
//
#include <hip/hip_runtime.h>
#include <hip/hip_bf16.h>

#define N_NODES  100000
#define N_EDGES  1600000
#define N_GRAPHS 2000
#define N_FEAT   13
#define HID      128

// -------------------- degree / dinv --------------------
__global__ void k_deg(const int* __restrict__ dst, int* __restrict__ indeg, int E) {
    int e = blockIdx.x * 256 + threadIdx.x;
    if (e < E) atomicAdd(&indeg[dst[e]], 1);
}

__global__ void k_dinv(const int* __restrict__ indeg, float* __restrict__ dinv, int n) {
    int i = blockIdx.x * 256 + threadIdx.x;
    if (i < n) dinv[i] = rsqrtf((float)(indeg[i] + 1));   // +1 self loop
}

// -------------------- scans (exclusive) --------------------
__global__ void k_scan1(const int* __restrict__ in, int* __restrict__ out,
                        int* __restrict__ bsum, int n) {
    __shared__ int ts[256];
    int t = threadIdx.x;
    int base = blockIdx.x * 1024 + t * 4;
    int v0 = (base + 0 < n) ? in[base + 0] : 0;
    int v1 = (base + 1 < n) ? in[base + 1] : 0;
    int v2 = (base + 2 < n) ? in[base + 2] : 0;
    int v3 = (base + 3 < n) ? in[base + 3] : 0;
    int s = v0 + v1 + v2 + v3;
    ts[t] = s;
    __syncthreads();
    for (int o = 1; o < 256; o <<= 1) {
        int x = (t >= o) ? ts[t - o] : 0;
        __syncthreads();
        ts[t] += x;
        __syncthreads();
    }
    if (t == 255) bsum[blockIdx.x] = ts[255];
    int run = ts[t] - s;
    if (base + 0 < n) out[base + 0] = run; run += v0;
    if (base + 1 < n) out[base + 1] = run; run += v1;
    if (base + 2 < n) out[base + 2] = run; run += v2;
    if (base + 3 < n) out[base + 3] = run;
}

__global__ void k_scan_block(const int* __restrict__ in, int* __restrict__ out, int len) {
    __shared__ int ts[256];
    int t = threadIdx.x;
    int v[8];
    int s = 0;
#pragma unroll
    for (int j = 0; j < 8; j++) {
        int i = t * 8 + j;
        v[j] = (i < len) ? in[i] : 0;
        s += v[j];
    }
    ts[t] = s;
    __syncthreads();
    for (int o = 1; o < 256; o <<= 1) {
        int x = (t >= o) ? ts[t - o] : 0;
        __syncthreads();
        ts[t] += x;
        __syncthreads();
    }
    int run = ts[t] - s;
#pragma unroll
    for (int j = 0; j < 8; j++) {
        int i = t * 8 + j;
        if (i < len) out[i] = run;
        run += v[j];
    }
}

__global__ void k_scan3(int* __restrict__ out, const int* __restrict__ bpre, int n) {
    int i = blockIdx.x * 256 + threadIdx.x;
    if (i < n) out[i] += bpre[i >> 10];
}

// -------------------- CSR fill (per-node cursors: low contention) --------------------
__global__ void k_fill(const int* __restrict__ src, const int* __restrict__ dst,
                       const int* __restrict__ off, int* __restrict__ cursor,
                       int* __restrict__ csr, int E) {
    int e = blockIdx.x * 256 + threadIdx.x;
    if (e < E) {
        int d = dst[e];
        int p = off[d] + atomicAdd(&cursor[d], 1);
        csr[p] = src[e];
    }
}

// -------------------- layer 0: xs = dinv * x, padded to 16 cols --------------------
__global__ void k_scale_pad(const float* __restrict__ x, const float* __restrict__ dinv,
                            float* __restrict__ xs, int n) {
    int i = blockIdx.x * 256 + threadIdx.x;
    if (i >= n) return;
    float dv = dinv[i];
    float r[16];
#pragma unroll
    for (int k = 0; k < N_FEAT; k++) r[k] = dv * x[i * N_FEAT + k];
    r[13] = r[14] = r[15] = 0.f;
    float4* o = (float4*)&xs[i * 16];
    o[0] = float4{r[0], r[1], r[2], r[3]};
    o[1] = float4{r[4], r[5], r[6], r[7]};
    o[2] = float4{r[8], r[9], r[10], r[11]};
    o[3] = float4{r[12], r[13], r[14], r[15]};
}

// -------------------- layer 0 gather on 16-wide rows (quarter-wave per dst) ----------
__global__ void k_gather13(const float* __restrict__ xs, const int* __restrict__ off,
                           const int* __restrict__ indeg, const int* __restrict__ csr,
                           const float* __restrict__ dinv, float* __restrict__ agg, int n) {
    int lane = threadIdx.x & 63;
    int q = lane >> 4, l4 = lane & 15;
    int d = blockIdx.x * 16 + (threadIdx.x >> 6) * 4 + q;
    if (d >= n) return;
    int s0 = off[d], c = indeg[d];
    float acc = xs[(size_t)d * 16 + l4];   // self term (already dinv[d]-scaled)
    int p = 0;
    for (; p + 3 < c; p += 4) {
        int sa = csr[s0 + p], sb = csr[s0 + p + 1];
        int sc_ = csr[s0 + p + 2], sd_ = csr[s0 + p + 3];
        float va = xs[(size_t)sa * 16 + l4];
        float vb = xs[(size_t)sb * 16 + l4];
        float vc = xs[(size_t)sc_ * 16 + l4];
        float vd = xs[(size_t)sd_ * 16 + l4];
        acc += (va + vb) + (vc + vd);
    }
    for (; p < c; p++) acc += xs[(size_t)csr[s0 + p] * 16 + l4];
    agg[(size_t)d * 16 + l4] = dinv[d] * acc;
}

// -------------------- layer 0 GEMM: h0 = relu(agg @ W0 + b0), K=13 --------------------
__global__ void k_gemm13(const float* __restrict__ agg, const float* __restrict__ W,
                         const float* __restrict__ b, float* __restrict__ h, int n) {
    __shared__ float Ws[N_FEAT * HID];
    for (int i = threadIdx.x; i < N_FEAT * HID; i += 256) Ws[i] = W[i];
    __syncthreads();
    int i = blockIdx.x * 2 + (threadIdx.x >> 7);
    int f = threadIdx.x & 127;
    if (i >= n) return;
    float acc = b[f];
#pragma unroll
    for (int k = 0; k < N_FEAT; k++) acc += agg[(size_t)i * 16 + k] * Ws[k * HID + f];
    h[(size_t)i * HID + f] = fmaxf(acc, 0.f);
}

// -------------------- fp32 -> bf16 RTNE --------------------
__device__ __forceinline__ unsigned short f2bf(float f) {
    unsigned int b = __float_as_uint(f);
    b += 0x7fffu + ((b >> 16) & 1u);
    return (unsigned short)(b >> 16);
}

// -------------------- GEMM 128x128: ubf = bf16( dinv * (X @ W) ) --------------------
__global__ __launch_bounds__(256) void k_gemm128(const float* __restrict__ X,
                                                 const float* __restrict__ W,
                                                 const float* __restrict__ dinv,
                                                 unsigned short* __restrict__ ubf, int n) {
    __shared__ float Ws[HID * HID];   // 64 KB
    __shared__ float Xs[32 * HID];    // 16 KB
    int t = threadIdx.x;
    {
        const float4* W4 = (const float4*)W;
        float4* Ws4 = (float4*)Ws;
#pragma unroll
        for (int i = 0; i < 16; i++) Ws4[t + 256 * i] = W4[t + 256 * i];
    }
    int nb = blockIdx.x * 32;
    {
        const float4* X4 = (const float4*)X;
        float4* Xs4 = (float4*)Xs;
#pragma unroll
        for (int i = 0; i < 4; i++) {
            int idx = t + 256 * i;
            int node = idx >> 5, c4 = idx & 31;
            int g = nb + node;
            Xs4[idx] = (g < n) ? X4[(size_t)g * 32 + c4] : float4{0.f, 0.f, 0.f, 0.f};
        }
    }
    __syncthreads();

    int fg = (t & 31) * 4;
    int nl = (t >> 5) * 4;
    float acc[4][4];
#pragma unroll
    for (int j = 0; j < 4; j++)
#pragma unroll
        for (int q = 0; q < 4; q++) acc[j][q] = 0.f;

#pragma unroll 8
    for (int k = 0; k < HID; k++) {
        float4 w = *(const float4*)&Ws[k * HID + fg];
#pragma unroll
        for (int j = 0; j < 4; j++) {
            float xv = Xs[(nl + j) * HID + k];
            acc[j][0] += xv * w.x;
            acc[j][1] += xv * w.y;
            acc[j][2] += xv * w.z;
            acc[j][3] += xv * w.w;
        }
    }
#pragma unroll
    for (int j = 0; j < 4; j++) {
        int g = nb + nl + j;
        if (g < n) {
            float dv = dinv[g];
            ushort4 r;
            r.x = f2bf(dv * acc[j][0]);
            r.y = f2bf(dv * acc[j][1]);
            r.z = f2bf(dv * acc[j][2]);
            r.w = f2bf(dv * acc[j][3]);
            *(ushort4*)&ubf[(size_t)g * HID + fg] = r;
        }
    }
}

// ---- gather over bf16 rows: half-wave per dst, 8-deep independent load pipeline ----
// No cross-lane ops: each half-wave (32 lanes x uint2 = one 256B row slice) owns a node.
__global__ void k_gather128(const unsigned int* __restrict__ ubf, const int* __restrict__ off,
                            const int* __restrict__ indeg, const int* __restrict__ csr,
                            const float* __restrict__ dinv, const float* __restrict__ bias,
                            float* __restrict__ y, int n, int relu) {
    int wv = threadIdx.x >> 6;
    int lane = threadIdx.x & 63;
    int half = lane >> 5, l2 = lane & 31;
    int d = blockIdx.x * 8 + wv * 2 + half;   // 8 nodes per 256-thread block
    if (d >= n) return;
    int s0 = off[d], c = indeg[d];
    const uint2* U = (const uint2*)ubf;   // one row = 32 uint2 (128 bf16)

    // self term
    uint2 sv = U[(size_t)d * 32 + l2];
    float a0 = __uint_as_float(sv.x << 16);
    float a1 = __uint_as_float(sv.x & 0xffff0000u);
    float a2 = __uint_as_float(sv.y << 16);
    float a3 = __uint_as_float(sv.y & 0xffff0000u);

    int p = 0;
    for (; p + 7 < c; p += 8) {        // 8 independent index+row chains in flight
        int s_[8];
#pragma unroll
        for (int j = 0; j < 8; j++) s_[j] = csr[s0 + p + j];
        uint2 v[8];
#pragma unroll
        for (int j = 0; j < 8; j++) v[j] = U[(size_t)s_[j] * 32 + l2];
#pragma unroll
        for (int j = 0; j < 8; j++) {
            a0 += __uint_as_float(v[j].x << 16);
            a1 += __uint_as_float(v[j].x & 0xffff0000u);
            a2 += __uint_as_float(v[j].y << 16);
            a3 += __uint_as_float(v[j].y & 0xffff0000u);
        }
    }
    if (p + 3 < c) {                   // 4-deep step
        int s_[4];
#pragma unroll
        for (int j = 0; j < 4; j++) s_[j] = csr[s0 + p + j];
        uint2 v[4];
#pragma unroll
        for (int j = 0; j < 4; j++) v[j] = U[(size_t)s_[j] * 32 + l2];
#pragma unroll
        for (int j = 0; j < 4; j++) {
            a0 += __uint_as_float(v[j].x << 16);
            a1 += __uint_as_float(v[j].x & 0xffff0000u);
            a2 += __uint_as_float(v[j].y << 16);
            a3 += __uint_as_float(v[j].y & 0xffff0000u);
        }
        p += 4;
    }
    for (; p < c; p++) {
        int s = csr[s0 + p];
        uint2 v = U[(size_t)s * 32 + l2];
        a0 += __uint_as_float(v.x << 16);
        a1 += __uint_as_float(v.x & 0xffff0000u);
        a2 += __uint_as_float(v.y << 16);
        a3 += __uint_as_float(v.y & 0xffff0000u);
    }

    float dv = dinv[d];
    float4 bb = *(const float4*)&bias[l2 * 4];
    float4 r = {dv * a0 + bb.x, dv * a1 + bb.y, dv * a2 + bb.z, dv * a3 + bb.w};
    if (relu) {
        r.x = fmaxf(r.x, 0.f); r.y = fmaxf(r.y, 0.f);
        r.z = fmaxf(r.z, 0.f); r.w = fmaxf(r.w, 0.f);
    }
    *(float4*)&y[(size_t)d * HID + l2 * 4] = r;
}

// -------------------- pooling --------------------
__global__ void k_cnt(const int* __restrict__ batch, int* __restrict__ cnt, int n) {
    int i = blockIdx.x * 256 + threadIdx.x;
    if (i < n) atomicAdd(&cnt[batch[i]], 1);
}

__global__ void k_pool(const float* __restrict__ h, const int* __restrict__ goff,
                       const int* __restrict__ cnt, float* __restrict__ pooledm) {
    int g = blockIdx.x;
    int t = threadIdx.x;   // 128
    int s = goff[g], c = cnt[g];
    float acc = 0.f;
    for (int i = s; i < s + c; i++) acc += h[(size_t)i * HID + t];
    pooledm[g * HID + t] = acc / (float)max(c, 1);
}

// -------------------- MLP head --------------------
__global__ void k_fc0(const float* __restrict__ in, const float* __restrict__ W,
                      const float* __restrict__ b, float* __restrict__ out) {
    __shared__ float row[128];
    int g = blockIdx.x, t = threadIdx.x;   // 256 threads
    if (t < 128) row[t] = in[g * 128 + t];
    __syncthreads();
    float acc = 0.f;
#pragma unroll 8
    for (int k = 0; k < 128; k++) acc += row[k] * W[k * 256 + t];
    acc += b[t];
    out[g * 256 + t] = fmaxf(acc, 0.f);
}

__global__ void k_fc1(const float* __restrict__ in, const float* __restrict__ W,
                      const float* __restrict__ b, float* __restrict__ out) {
    __shared__ float row[256];
    int g = blockIdx.x, t = threadIdx.x;   // 128 threads
    row[t] = in[g * 256 + t];
    row[t + 128] = in[g * 256 + t + 128];
    __syncthreads();
    float acc = 0.f;
#pragma unroll 8
    for (int k = 0; k < 256; k++) acc += row[k] * W[k * 128 + t];
    acc += b[t];
    out[g * 128 + t] = fmaxf(acc, 0.f);
}

__global__ void k_fco(const float* __restrict__ in, const float* __restrict__ Wo,
                      const float* __restrict__ bo, float* __restrict__ out) {
    int g = blockIdx.x, t = threadIdx.x;   // 64 threads = 1 wave
    float acc = in[g * 128 + t] * Wo[t] + in[g * 128 + 64 + t] * Wo[64 + t];
    for (int s = 32; s > 0; s >>= 1) acc += __shfl_down(acc, s);
    if (t == 0) out[g] = acc + bo[0];
}

// -------------------- launch --------------------
extern "C" void kernel_launch(void* const* d_in, const int* in_sizes, int n_in,
                              void* d_out, int out_size, void* d_ws, size_t ws_size,
                              hipStream_t stream) {
    const float* x   = (const float*)d_in[0];
    const int* ei    = (const int*)d_in[1];
    const int* src   = ei;
    const int* dst   = ei + N_EDGES;
    const int* batch = (const int*)d_in[2];
    const float* W0 = (const float*)d_in[3];  const float* b0 = (const float*)d_in[4];
    const float* W1 = (const float*)d_in[5];  const float* b1 = (const float*)d_in[6];
    const float* W2 = (const float*)d_in[7];  const float* b2 = (const float*)d_in[8];
    const float* Wf0 = (const float*)d_in[9];  const float* bf0 = (const float*)d_in[10];
    const float* Wf1 = (const float*)d_in[11]; const float* bf1 = (const float*)d_in[12];
    const float* Wo = (const float*)d_in[13];  const float* bo = (const float*)d_in[14];
    float* out = (float*)d_out;

    char* w = (char*)d_ws;
    size_t o = 0;
    auto take = [&](size_t bytes) -> char* {
        char* p = w + o;
        o += (bytes + 255) & ~(size_t)255;
        return p;
    };
    int* indeg    = (int*)take((size_t)N_NODES * 4);
    int* cursor   = (int*)take((size_t)N_NODES * 4);
    int* off      = (int*)take((size_t)N_NODES * 4);
    int* bsum     = (int*)take(256 * 4);
    int* bpre     = (int*)take(256 * 4);
    int* csr      = (int*)take((size_t)N_EDGES * 4);
    float* dinv   = (float*)take((size_t)N_NODES * 4);
    int* cnt      = (int*)take((size_t)N_GRAPHS * 4);
    int* goff     = (int*)take((size_t)N_GRAPHS * 4);
    float* bufA   = (float*)take((size_t)N_NODES * HID * 4);
    float* bufB   = (float*)take((size_t)N_NODES * HID * 4);
    unsigned short* ubf = (unsigned short*)take((size_t)N_NODES * HID * 2);
    float* pooledm= (float*)take((size_t)N_GRAPHS * HID * 4);
    float* fc0    = (float*)take((size_t)N_GRAPHS * 256 * 4);
    float* fc1    = (float*)take((size_t)N_GRAPHS * HID * 4);
    // xs/agg alias bufB (dead before first gather128 write to bufB)
    float* xs  = bufB;
    float* agg = bufB + (size_t)N_NODES * 16;

    hipMemsetAsync(indeg, 0, (size_t)N_NODES * 4, stream);
    hipMemsetAsync(cursor, 0, (size_t)N_NODES * 4, stream);
    hipMemsetAsync(cnt, 0, (size_t)N_GRAPHS * 4, stream);

    // topology (shared by all 3 conv layers)
    k_deg<<<(N_EDGES + 255) / 256, 256, 0, stream>>>(dst, indeg, N_EDGES);
    int nb1 = (N_NODES + 1023) / 1024;
    k_scan1<<<nb1, 256, 0, stream>>>(indeg, off, bsum, N_NODES);
    k_scan_block<<<1, 256, 0, stream>>>(bsum, bpre, nb1);
    k_scan3<<<(N_NODES + 255) / 256, 256, 0, stream>>>(off, bpre, N_NODES);
    k_fill<<<(N_EDGES + 255) / 256, 256, 0, stream>>>(src, dst, off, cursor, csr, N_EDGES);
    k_dinv<<<(N_NODES + 255) / 256, 256, 0, stream>>>(indeg, dinv, N_NODES);
    k_cnt<<<(N_NODES + 255) / 256, 256, 0, stream>>>(batch, cnt, N_NODES);
    k_scan_block<<<1, 256, 0, stream>>>(cnt, goff, N_GRAPHS);

    // layer 0: aggregate 13-wide first, then GEMM
    k_scale_pad<<<(N_NODES + 255) / 256, 256, 0, stream>>>(x, dinv, xs, N_NODES);
    k_gather13<<<(N_NODES + 15) / 16, 256, 0, stream>>>(xs, off, indeg, csr, dinv, agg, N_NODES);
    k_gemm13<<<(N_NODES + 1) / 2, 256, 0, stream>>>(agg, W0, b0, bufA, N_NODES);
    // layer 1
    k_gemm128<<<(N_NODES + 31) / 32, 256, 0, stream>>>(bufA, W1, dinv, ubf, N_NODES);
    k_gather128<<<(N_NODES + 7) / 8, 256, 0, stream>>>((const unsigned int*)ubf, off, indeg, csr, dinv, b1, bufB, N_NODES, 1);
    // layer 2 (no relu)
    k_gemm128<<<(N_NODES + 31) / 32, 256, 0, stream>>>(bufB, W2, dinv, ubf, N_NODES);
    k_gather128<<<(N_NODES + 7) / 8, 256, 0, stream>>>((const unsigned int*)ubf, off, indeg, csr, dinv, b2, bufA, N_NODES, 0);

    // pool + MLP head
    k_pool<<<N_GRAPHS, 128, 0, stream>>>(bufA, goff, cnt, pooledm);
    k_fc0<<<N_GRAPHS, 256, 0, stream>>>(pooledm, Wf0, bf0, fc0);
    k_fc1<<<N_GRAPHS, 128, 0, stream>>>(fc0, Wf1, bf1, fc1);
    k_fco<<<N_GRAPHS, 64, 0, stream>>>(fc1, Wo, bo, out);
}

// Round 6
// 492.922 us; speedup vs baseline: 1.7176x; 1.1588x over previous
//
#include <hip/hip_runtime.h>
#include <hip/hip_bf16.h>

#define N_NODES  100000
#define N_EDGES  1600000
#define N_GRAPHS 2000
#define N_FEAT   13
#define HID      128
#define NB       ((N_NODES + 127) / 128)   // 782 buckets of 128 nodes
#define NBLK     128                        // edge-partition blocks for the sort
#define N2       (NB * NBLK)                // 100096 (bucket,block) windows

// ============ contention-free counting sort of edges by dst bucket ============
// phase 1: per-block LDS histogram over buckets -> counts[block][bucket]
__global__ void k_hist1(const int* __restrict__ dst, int* __restrict__ counts, int E) {
    __shared__ int hist[NB];
    int k = blockIdx.x, t = threadIdx.x;
    for (int b = t; b < NB; b += 256) hist[b] = 0;
    __syncthreads();
    int epb = (E + NBLK - 1) / NBLK;
    int base = k * epb, lim = min(base + epb, E);
    for (int i = base + t; i < lim; i += 256) atomicAdd(&hist[dst[i] >> 7], 1);
    __syncthreads();
    for (int b = t; b < NB; b += 256) counts[k * NB + b] = hist[b];
}

// phase 2: transpose to bucket-major (coalesced write, L2-resident strided read)
__global__ void k_transp(const int* __restrict__ counts, int* __restrict__ countsT) {
    int i = blockIdx.x * 256 + threadIdx.x;   // i = b*NBLK + k
    if (i < N2) countsT[i] = counts[(i & (NBLK - 1)) * NB + (i >> 7)];
}

// phase 3 (after exclusive scan of countsT -> scT): scatter into bucket-contiguous bstore
__global__ void k_scatter(const int* __restrict__ src, const int* __restrict__ dst,
                          const int* __restrict__ scT, unsigned int* __restrict__ bstore, int E) {
    __shared__ int cnt[NB];
    int k = blockIdx.x, t = threadIdx.x;
    for (int b = t; b < NB; b += 256) cnt[b] = 0;
    __syncthreads();
    int epb = (E + NBLK - 1) / NBLK;
    int base = k * epb, lim = min(base + epb, E);
    for (int i = base + t; i < lim; i += 256) {
        int d = dst[i];
        int b = d >> 7;
        int r = atomicAdd(&cnt[b], 1);    // LDS rank within (bucket, block) window
        bstore[scT[b * NBLK + k] + r] = ((unsigned int)src[i] << 7) | (unsigned int)(d & 127);
    }
}

// phase 4: per-bucket node histogram -> indeg + dinv (no global atomics)
__global__ void k_bhist(const unsigned int* __restrict__ bstore, const int* __restrict__ scT,
                        int* __restrict__ indeg, float* __restrict__ dinv, int n, int E) {
    __shared__ int cnt[128];
    int b = blockIdx.x, t = threadIdx.x;
    if (t < 128) cnt[t] = 0;
    __syncthreads();
    int start = scT[b * NBLK];
    int end = (b + 1 < NB) ? scT[(b + 1) * NBLK] : E;
    for (int i = start + t; i < end; i += 256) atomicAdd(&cnt[bstore[i] & 127], 1);
    __syncthreads();
    int node = b * 128 + t;
    if (t < 128 && node < n) {
        indeg[node] = cnt[t];
        dinv[node] = rsqrtf((float)(cnt[t] + 1));   // +1 self loop
    }
}

// phase 5: per-bucket CSR fill; writes confined to the bucket's contiguous csr window
__global__ void k_bfill(const unsigned int* __restrict__ bstore, const int* __restrict__ scT,
                        const int* __restrict__ off, int* __restrict__ csr, int n, int E) {
    __shared__ int cur[128];
    __shared__ int loff[128];
    int b = blockIdx.x, t = threadIdx.x;
    if (t < 128) {
        cur[t] = 0;
        int node = b * 128 + t;
        loff[t] = (node < n) ? off[node] : 0;
    }
    __syncthreads();
    int start = scT[b * NBLK];
    int end = (b + 1 < NB) ? scT[(b + 1) * NBLK] : E;
    for (int i = start + t; i < end; i += 256) {
        unsigned int e = bstore[i];
        int dl = e & 127;
        int p = loff[dl] + atomicAdd(&cur[dl], 1);
        csr[p] = (int)(e >> 7);
    }
}

// -------------------- scans (exclusive) --------------------
__global__ void k_scan1(const int* __restrict__ in, int* __restrict__ out,
                        int* __restrict__ bsum, int n) {
    __shared__ int ts[256];
    int t = threadIdx.x;
    int base = blockIdx.x * 1024 + t * 4;
    int v0 = (base + 0 < n) ? in[base + 0] : 0;
    int v1 = (base + 1 < n) ? in[base + 1] : 0;
    int v2 = (base + 2 < n) ? in[base + 2] : 0;
    int v3 = (base + 3 < n) ? in[base + 3] : 0;
    int s = v0 + v1 + v2 + v3;
    ts[t] = s;
    __syncthreads();
    for (int o = 1; o < 256; o <<= 1) {
        int x = (t >= o) ? ts[t - o] : 0;
        __syncthreads();
        ts[t] += x;
        __syncthreads();
    }
    if (t == 255) bsum[blockIdx.x] = ts[255];
    int run = ts[t] - s;
    if (base + 0 < n) out[base + 0] = run; run += v0;
    if (base + 1 < n) out[base + 1] = run; run += v1;
    if (base + 2 < n) out[base + 2] = run; run += v2;
    if (base + 3 < n) out[base + 3] = run;
}

__global__ void k_scan_block(const int* __restrict__ in, int* __restrict__ out, int len) {
    __shared__ int ts[256];
    int t = threadIdx.x;
    int v[8];
    int s = 0;
#pragma unroll
    for (int j = 0; j < 8; j++) {
        int i = t * 8 + j;
        v[j] = (i < len) ? in[i] : 0;
        s += v[j];
    }
    ts[t] = s;
    __syncthreads();
    for (int o = 1; o < 256; o <<= 1) {
        int x = (t >= o) ? ts[t - o] : 0;
        __syncthreads();
        ts[t] += x;
        __syncthreads();
    }
    int run = ts[t] - s;
#pragma unroll
    for (int j = 0; j < 8; j++) {
        int i = t * 8 + j;
        if (i < len) out[i] = run;
        run += v[j];
    }
}

__global__ void k_scan3(int* __restrict__ out, const int* __restrict__ bpre, int n) {
    int i = blockIdx.x * 256 + threadIdx.x;
    if (i < n) out[i] += bpre[i >> 10];
}

// -------------------- layer 0: xs = dinv * x, padded to 16 cols --------------------
__global__ void k_scale_pad(const float* __restrict__ x, const float* __restrict__ dinv,
                            float* __restrict__ xs, int n) {
    int i = blockIdx.x * 256 + threadIdx.x;
    if (i >= n) return;
    float dv = dinv[i];
    float r[16];
#pragma unroll
    for (int k = 0; k < N_FEAT; k++) r[k] = dv * x[i * N_FEAT + k];
    r[13] = r[14] = r[15] = 0.f;
    float4* o = (float4*)&xs[i * 16];
    o[0] = float4{r[0], r[1], r[2], r[3]};
    o[1] = float4{r[4], r[5], r[6], r[7]};
    o[2] = float4{r[8], r[9], r[10], r[11]};
    o[3] = float4{r[12], r[13], r[14], r[15]};
}

// -------------------- layer 0 gather on 16-wide rows (quarter-wave per dst) ----------
__global__ void k_gather13(const float* __restrict__ xs, const int* __restrict__ off,
                           const int* __restrict__ indeg, const int* __restrict__ csr,
                           const float* __restrict__ dinv, float* __restrict__ agg, int n) {
    int lane = threadIdx.x & 63;
    int q = lane >> 4, l4 = lane & 15;
    int d = blockIdx.x * 16 + (threadIdx.x >> 6) * 4 + q;
    if (d >= n) return;
    int s0 = off[d], c = indeg[d];
    float acc = xs[(size_t)d * 16 + l4];   // self term (already dinv[d]-scaled)
    int p = 0;
    for (; p + 3 < c; p += 4) {
        int sa = csr[s0 + p], sb = csr[s0 + p + 1];
        int sc_ = csr[s0 + p + 2], sd_ = csr[s0 + p + 3];
        float va = xs[(size_t)sa * 16 + l4];
        float vb = xs[(size_t)sb * 16 + l4];
        float vc = xs[(size_t)sc_ * 16 + l4];
        float vd = xs[(size_t)sd_ * 16 + l4];
        acc += (va + vb) + (vc + vd);
    }
    for (; p < c; p++) acc += xs[(size_t)csr[s0 + p] * 16 + l4];
    agg[(size_t)d * 16 + l4] = dinv[d] * acc;
}

// -------------------- layer 0 GEMM: h0 = relu(agg @ W0 + b0), K=13 --------------------
__global__ void k_gemm13(const float* __restrict__ agg, const float* __restrict__ W,
                         const float* __restrict__ b, float* __restrict__ h, int n) {
    __shared__ float Ws[N_FEAT * HID];
    for (int i = threadIdx.x; i < N_FEAT * HID; i += 256) Ws[i] = W[i];
    __syncthreads();
    int i = blockIdx.x * 2 + (threadIdx.x >> 7);
    int f = threadIdx.x & 127;
    if (i >= n) return;
    float acc = b[f];
#pragma unroll
    for (int k = 0; k < N_FEAT; k++) acc += agg[(size_t)i * 16 + k] * Ws[k * HID + f];
    h[(size_t)i * HID + f] = fmaxf(acc, 0.f);
}

// -------------------- fp32 -> bf16 RTNE --------------------
__device__ __forceinline__ unsigned short f2bf(float f) {
    unsigned int b = __float_as_uint(f);
    b += 0x7fffu + ((b >> 16) & 1u);
    return (unsigned short)(b >> 16);
}

// -------------------- GEMM 128x128: ubf = bf16( dinv * (X @ W) ) --------------------
__global__ __launch_bounds__(256) void k_gemm128(const float* __restrict__ X,
                                                 const float* __restrict__ W,
                                                 const float* __restrict__ dinv,
                                                 unsigned short* __restrict__ ubf, int n) {
    __shared__ float Ws[HID * HID];   // 64 KB
    __shared__ float Xs[32 * HID];    // 16 KB
    int t = threadIdx.x;
    {
        const float4* W4 = (const float4*)W;
        float4* Ws4 = (float4*)Ws;
#pragma unroll
        for (int i = 0; i < 16; i++) Ws4[t + 256 * i] = W4[t + 256 * i];
    }
    int nb = blockIdx.x * 32;
    {
        const float4* X4 = (const float4*)X;
        float4* Xs4 = (float4*)Xs;
#pragma unroll
        for (int i = 0; i < 4; i++) {
            int idx = t + 256 * i;
            int node = idx >> 5, c4 = idx & 31;
            int g = nb + node;
            Xs4[idx] = (g < n) ? X4[(size_t)g * 32 + c4] : float4{0.f, 0.f, 0.f, 0.f};
        }
    }
    __syncthreads();

    int fg = (t & 31) * 4;
    int nl = (t >> 5) * 4;
    float acc[4][4];
#pragma unroll
    for (int j = 0; j < 4; j++)
#pragma unroll
        for (int q = 0; q < 4; q++) acc[j][q] = 0.f;

#pragma unroll 8
    for (int k = 0; k < HID; k++) {
        float4 w = *(const float4*)&Ws[k * HID + fg];
#pragma unroll
        for (int j = 0; j < 4; j++) {
            float xv = Xs[(nl + j) * HID + k];
            acc[j][0] += xv * w.x;
            acc[j][1] += xv * w.y;
            acc[j][2] += xv * w.z;
            acc[j][3] += xv * w.w;
        }
    }
#pragma unroll
    for (int j = 0; j < 4; j++) {
        int g = nb + nl + j;
        if (g < n) {
            float dv = dinv[g];
            ushort4 r;
            r.x = f2bf(dv * acc[j][0]);
            r.y = f2bf(dv * acc[j][1]);
            r.z = f2bf(dv * acc[j][2]);
            r.w = f2bf(dv * acc[j][3]);
            *(ushort4*)&ubf[(size_t)g * HID + fg] = r;
        }
    }
}

// ---- gather over bf16 rows: half-wave per dst, 8-deep independent load pipeline ----
__global__ void k_gather128(const unsigned int* __restrict__ ubf, const int* __restrict__ off,
                            const int* __restrict__ indeg, const int* __restrict__ csr,
                            const float* __restrict__ dinv, const float* __restrict__ bias,
                            float* __restrict__ y, int n, int relu) {
    int wv = threadIdx.x >> 6;
    int lane = threadIdx.x & 63;
    int half = lane >> 5, l2 = lane & 31;
    int d = blockIdx.x * 8 + wv * 2 + half;   // 8 nodes per 256-thread block
    if (d >= n) return;
    int s0 = off[d], c = indeg[d];
    const uint2* U = (const uint2*)ubf;   // one row = 32 uint2 (128 bf16)

    // self term
    uint2 sv = U[(size_t)d * 32 + l2];
    float a0 = __uint_as_float(sv.x << 16);
    float a1 = __uint_as_float(sv.x & 0xffff0000u);
    float a2 = __uint_as_float(sv.y << 16);
    float a3 = __uint_as_float(sv.y & 0xffff0000u);

    int p = 0;
    for (; p + 7 < c; p += 8) {        // 8 independent index+row chains in flight
        int s_[8];
#pragma unroll
        for (int j = 0; j < 8; j++) s_[j] = csr[s0 + p + j];
        uint2 v[8];
#pragma unroll
        for (int j = 0; j < 8; j++) v[j] = U[(size_t)s_[j] * 32 + l2];
#pragma unroll
        for (int j = 0; j < 8; j++) {
            a0 += __uint_as_float(v[j].x << 16);
            a1 += __uint_as_float(v[j].x & 0xffff0000u);
            a2 += __uint_as_float(v[j].y << 16);
            a3 += __uint_as_float(v[j].y & 0xffff0000u);
        }
    }
    if (p + 3 < c) {                   // 4-deep step
        int s_[4];
#pragma unroll
        for (int j = 0; j < 4; j++) s_[j] = csr[s0 + p + j];
        uint2 v[4];
#pragma unroll
        for (int j = 0; j < 4; j++) v[j] = U[(size_t)s_[j] * 32 + l2];
#pragma unroll
        for (int j = 0; j < 4; j++) {
            a0 += __uint_as_float(v[j].x << 16);
            a1 += __uint_as_float(v[j].x & 0xffff0000u);
            a2 += __uint_as_float(v[j].y << 16);
            a3 += __uint_as_float(v[j].y & 0xffff0000u);
        }
        p += 4;
    }
    for (; p < c; p++) {
        int s = csr[s0 + p];
        uint2 v = U[(size_t)s * 32 + l2];
        a0 += __uint_as_float(v.x << 16);
        a1 += __uint_as_float(v.x & 0xffff0000u);
        a2 += __uint_as_float(v.y << 16);
        a3 += __uint_as_float(v.y & 0xffff0000u);
    }

    float dv = dinv[d];
    float4 bb = *(const float4*)&bias[l2 * 4];
    float4 r = {dv * a0 + bb.x, dv * a1 + bb.y, dv * a2 + bb.z, dv * a3 + bb.w};
    if (relu) {
        r.x = fmaxf(r.x, 0.f); r.y = fmaxf(r.y, 0.f);
        r.z = fmaxf(r.z, 0.f); r.w = fmaxf(r.w, 0.f);
    }
    *(float4*)&y[(size_t)d * HID + l2 * 4] = r;
}

// -------------------- pooling --------------------
__global__ void k_cnt(const int* __restrict__ batch, int* __restrict__ cnt, int n) {
    int i = blockIdx.x * 256 + threadIdx.x;
    if (i < n) atomicAdd(&cnt[batch[i]], 1);
}

__global__ void k_pool(const float* __restrict__ h, const int* __restrict__ goff,
                       const int* __restrict__ cnt, float* __restrict__ pooledm) {
    int g = blockIdx.x;
    int t = threadIdx.x;   // 128
    int s = goff[g], c = cnt[g];
    float acc = 0.f;
    for (int i = s; i < s + c; i++) acc += h[(size_t)i * HID + t];
    pooledm[g * HID + t] = acc / (float)max(c, 1);
}

// -------------------- MLP head --------------------
__global__ void k_fc0(const float* __restrict__ in, const float* __restrict__ W,
                      const float* __restrict__ b, float* __restrict__ out) {
    __shared__ float row[128];
    int g = blockIdx.x, t = threadIdx.x;   // 256 threads
    if (t < 128) row[t] = in[g * 128 + t];
    __syncthreads();
    float acc = 0.f;
#pragma unroll 8
    for (int k = 0; k < 128; k++) acc += row[k] * W[k * 256 + t];
    acc += b[t];
    out[g * 256 + t] = fmaxf(acc, 0.f);
}

__global__ void k_fc1(const float* __restrict__ in, const float* __restrict__ W,
                      const float* __restrict__ b, float* __restrict__ out) {
    __shared__ float row[256];
    int g = blockIdx.x, t = threadIdx.x;   // 128 threads
    row[t] = in[g * 256 + t];
    row[t + 128] = in[g * 256 + t + 128];
    __syncthreads();
    float acc = 0.f;
#pragma unroll 8
    for (int k = 0; k < 256; k++) acc += row[k] * W[k * 128 + t];
    acc += b[t];
    out[g * 128 + t] = fmaxf(acc, 0.f);
}

__global__ void k_fco(const float* __restrict__ in, const float* __restrict__ Wo,
                      const float* __restrict__ bo, float* __restrict__ out) {
    int g = blockIdx.x, t = threadIdx.x;   // 64 threads = 1 wave
    float acc = in[g * 128 + t] * Wo[t] + in[g * 128 + 64 + t] * Wo[64 + t];
    for (int s = 32; s > 0; s >>= 1) acc += __shfl_down(acc, s);
    if (t == 0) out[g] = acc + bo[0];
}

// -------------------- launch --------------------
extern "C" void kernel_launch(void* const* d_in, const int* in_sizes, int n_in,
                              void* d_out, int out_size, void* d_ws, size_t ws_size,
                              hipStream_t stream) {
    const float* x   = (const float*)d_in[0];
    const int* ei    = (const int*)d_in[1];
    const int* src   = ei;
    const int* dst   = ei + N_EDGES;
    const int* batch = (const int*)d_in[2];
    const float* W0 = (const float*)d_in[3];  const float* b0 = (const float*)d_in[4];
    const float* W1 = (const float*)d_in[5];  const float* b1 = (const float*)d_in[6];
    const float* W2 = (const float*)d_in[7];  const float* b2 = (const float*)d_in[8];
    const float* Wf0 = (const float*)d_in[9];  const float* bf0 = (const float*)d_in[10];
    const float* Wf1 = (const float*)d_in[11]; const float* bf1 = (const float*)d_in[12];
    const float* Wo = (const float*)d_in[13];  const float* bo = (const float*)d_in[14];
    float* out = (float*)d_out;

    char* w = (char*)d_ws;
    size_t o = 0;
    auto take = [&](size_t bytes) -> char* {
        char* p = w + o;
        o += (bytes + 255) & ~(size_t)255;
        return p;
    };
    int* indeg    = (int*)take((size_t)N_NODES * 4);
    int* off      = (int*)take((size_t)N_NODES * 4);
    int* counts   = (int*)take((size_t)N2 * 4);
    int* countsT  = (int*)take((size_t)N2 * 4);
    int* scT      = (int*)take((size_t)N2 * 4);
    int* bsum     = (int*)take(256 * 4);
    int* bpre     = (int*)take(256 * 4);
    int* csr      = (int*)take((size_t)N_EDGES * 4);
    float* dinv   = (float*)take((size_t)N_NODES * 4);
    int* cnt      = (int*)take((size_t)N_GRAPHS * 4);
    int* goff     = (int*)take((size_t)N_GRAPHS * 4);
    float* bufA   = (float*)take((size_t)N_NODES * HID * 4);
    float* bufB   = (float*)take((size_t)N_NODES * HID * 4);
    unsigned short* ubf = (unsigned short*)take((size_t)N_NODES * HID * 2);
    float* pooledm= (float*)take((size_t)N_GRAPHS * HID * 4);
    float* fc0    = (float*)take((size_t)N_GRAPHS * 256 * 4);
    float* fc1    = (float*)take((size_t)N_GRAPHS * HID * 4);
    // bstore (6.4MB) aliases ubf (25.6MB): bstore dead after k_bfill; ubf written later
    unsigned int* bstore = (unsigned int*)ubf;
    // xs/agg alias bufB (dead before first gather128 write to bufB)
    float* xs  = bufB;
    float* agg = bufB + (size_t)N_NODES * 16;

    hipMemsetAsync(cnt, 0, (size_t)N_GRAPHS * 4, stream);

    // ---- topology: contention-free counting sort by dst bucket ----
    k_hist1<<<NBLK, 256, 0, stream>>>(dst, counts, N_EDGES);
    k_transp<<<(N2 + 255) / 256, 256, 0, stream>>>(counts, countsT);
    int nb2 = (N2 + 1023) / 1024;
    k_scan1<<<nb2, 256, 0, stream>>>(countsT, scT, bsum, N2);
    k_scan_block<<<1, 256, 0, stream>>>(bsum, bpre, nb2);
    k_scan3<<<(N2 + 255) / 256, 256, 0, stream>>>(scT, bpre, N2);
    k_scatter<<<NBLK, 256, 0, stream>>>(src, dst, scT, bstore, N_EDGES);
    k_bhist<<<NB, 256, 0, stream>>>(bstore, scT, indeg, dinv, N_NODES, N_EDGES);
    int nb1 = (N_NODES + 1023) / 1024;
    k_scan1<<<nb1, 256, 0, stream>>>(indeg, off, bsum, N_NODES);
    k_scan_block<<<1, 256, 0, stream>>>(bsum, bpre, nb1);
    k_scan3<<<(N_NODES + 255) / 256, 256, 0, stream>>>(off, bpre, N_NODES);
    k_bfill<<<NB, 256, 0, stream>>>(bstore, scT, off, csr, N_NODES, N_EDGES);
    k_cnt<<<(N_NODES + 255) / 256, 256, 0, stream>>>(batch, cnt, N_NODES);
    k_scan_block<<<1, 256, 0, stream>>>(cnt, goff, N_GRAPHS);

    // layer 0: aggregate 13-wide first, then GEMM
    k_scale_pad<<<(N_NODES + 255) / 256, 256, 0, stream>>>(x, dinv, xs, N_NODES);
    k_gather13<<<(N_NODES + 15) / 16, 256, 0, stream>>>(xs, off, indeg, csr, dinv, agg, N_NODES);
    k_gemm13<<<(N_NODES + 1) / 2, 256, 0, stream>>>(agg, W0, b0, bufA, N_NODES);
    // layer 1
    k_gemm128<<<(N_NODES + 31) / 32, 256, 0, stream>>>(bufA, W1, dinv, ubf, N_NODES);
    k_gather128<<<(N_NODES + 7) / 8, 256, 0, stream>>>((const unsigned int*)ubf, off, indeg, csr, dinv, b1, bufB, N_NODES, 1);
    // layer 2 (no relu)
    k_gemm128<<<(N_NODES + 31) / 32, 256, 0, stream>>>(bufB, W2, dinv, ubf, N_NODES);
    k_gather128<<<(N_NODES + 7) / 8, 256, 0, stream>>>((const unsigned int*)ubf, off, indeg, csr, dinv, b2, bufA, N_NODES, 0);

    // pool + MLP head
    k_pool<<<N_GRAPHS, 128, 0, stream>>>(bufA, goff, cnt, pooledm);
    k_fc0<<<N_GRAPHS, 256, 0, stream>>>(pooledm, Wf0, bf0, fc0);
    k_fc1<<<N_GRAPHS, 128, 0, stream>>>(fc0, Wf1, bf1, fc1);
    k_fco<<<N_GRAPHS, 64, 0, stream>>>(fc1, Wo, bo, out);
}

// Round 7
// 430.571 us; speedup vs baseline: 1.9664x; 1.1448x over previous
//
#include <hip/hip_runtime.h>
#include <hip/hip_bf16.h>

#define N_NODES  100000
#define N_EDGES  1600000
#define N_GRAPHS 2000
#define N_FEAT   13
#define HID      128
#define NB       ((N_NODES + 127) / 128)   // 782 buckets of 128 nodes
#define NBLK     128                        // edge-partition blocks for the sort
#define N2       (NB * NBLK)                // 100096 (bucket,block) windows

typedef __attribute__((ext_vector_type(8))) short bf16x8;   // 8 bf16 = 4 VGPRs
typedef __attribute__((ext_vector_type(4))) float f32x4;

// ============ contention-free counting sort of edges by dst bucket ============
__global__ void k_hist1(const int* __restrict__ dst, int* __restrict__ counts, int E) {
    __shared__ int hist[NB];
    int k = blockIdx.x, t = threadIdx.x;
    for (int b = t; b < NB; b += 256) hist[b] = 0;
    __syncthreads();
    int epb = (E + NBLK - 1) / NBLK;
    int base = k * epb, lim = min(base + epb, E);
    for (int i = base + t; i < lim; i += 256) atomicAdd(&hist[dst[i] >> 7], 1);
    __syncthreads();
    for (int b = t; b < NB; b += 256) counts[k * NB + b] = hist[b];
}

__global__ void k_transp(const int* __restrict__ counts, int* __restrict__ countsT) {
    int i = blockIdx.x * 256 + threadIdx.x;   // i = b*NBLK + k
    if (i < N2) countsT[i] = counts[(i & (NBLK - 1)) * NB + (i >> 7)];
}

__global__ void k_scatter(const int* __restrict__ src, const int* __restrict__ dst,
                          const int* __restrict__ scT, unsigned int* __restrict__ bstore, int E) {
    __shared__ int cnt[NB];
    int k = blockIdx.x, t = threadIdx.x;
    for (int b = t; b < NB; b += 256) cnt[b] = 0;
    __syncthreads();
    int epb = (E + NBLK - 1) / NBLK;
    int base = k * epb, lim = min(base + epb, E);
    for (int i = base + t; i < lim; i += 256) {
        int d = dst[i];
        int b = d >> 7;
        int r = atomicAdd(&cnt[b], 1);    // LDS rank within (bucket, block) window
        bstore[scT[b * NBLK + k] + r] = ((unsigned int)src[i] << 7) | (unsigned int)(d & 127);
    }
}

__global__ void k_bhist(const unsigned int* __restrict__ bstore, const int* __restrict__ scT,
                        int* __restrict__ indeg, float* __restrict__ dinv, int n, int E) {
    __shared__ int cnt[128];
    int b = blockIdx.x, t = threadIdx.x;
    if (t < 128) cnt[t] = 0;
    __syncthreads();
    int start = scT[b * NBLK];
    int end = (b + 1 < NB) ? scT[(b + 1) * NBLK] : E;
    for (int i = start + t; i < end; i += 256) atomicAdd(&cnt[bstore[i] & 127], 1);
    __syncthreads();
    int node = b * 128 + t;
    if (t < 128 && node < n) {
        indeg[node] = cnt[t];
        dinv[node] = rsqrtf((float)(cnt[t] + 1));   // +1 self loop
    }
}

__global__ void k_bfill(const unsigned int* __restrict__ bstore, const int* __restrict__ scT,
                        const int* __restrict__ off, int* __restrict__ csr, int n, int E) {
    __shared__ int cur[128];
    __shared__ int loff[128];
    int b = blockIdx.x, t = threadIdx.x;
    if (t < 128) {
        cur[t] = 0;
        int node = b * 128 + t;
        loff[t] = (node < n) ? off[node] : 0;
    }
    __syncthreads();
    int start = scT[b * NBLK];
    int end = (b + 1 < NB) ? scT[(b + 1) * NBLK] : E;
    for (int i = start + t; i < end; i += 256) {
        unsigned int e = bstore[i];
        int dl = e & 127;
        int p = loff[dl] + atomicAdd(&cur[dl], 1);
        csr[p] = (int)(e >> 7);
    }
}

// -------------------- scans (exclusive) --------------------
__global__ void k_scan1(const int* __restrict__ in, int* __restrict__ out,
                        int* __restrict__ bsum, int n) {
    __shared__ int ts[256];
    int t = threadIdx.x;
    int base = blockIdx.x * 1024 + t * 4;
    int v0 = (base + 0 < n) ? in[base + 0] : 0;
    int v1 = (base + 1 < n) ? in[base + 1] : 0;
    int v2 = (base + 2 < n) ? in[base + 2] : 0;
    int v3 = (base + 3 < n) ? in[base + 3] : 0;
    int s = v0 + v1 + v2 + v3;
    ts[t] = s;
    __syncthreads();
    for (int o = 1; o < 256; o <<= 1) {
        int x = (t >= o) ? ts[t - o] : 0;
        __syncthreads();
        ts[t] += x;
        __syncthreads();
    }
    if (t == 255) bsum[blockIdx.x] = ts[255];
    int run = ts[t] - s;
    if (base + 0 < n) out[base + 0] = run; run += v0;
    if (base + 1 < n) out[base + 1] = run; run += v1;
    if (base + 2 < n) out[base + 2] = run; run += v2;
    if (base + 3 < n) out[base + 3] = run;
}

__global__ void k_scan_block(const int* __restrict__ in, int* __restrict__ out, int len) {
    __shared__ int ts[256];
    int t = threadIdx.x;
    int v[8];
    int s = 0;
#pragma unroll
    for (int j = 0; j < 8; j++) {
        int i = t * 8 + j;
        v[j] = (i < len) ? in[i] : 0;
        s += v[j];
    }
    ts[t] = s;
    __syncthreads();
    for (int o = 1; o < 256; o <<= 1) {
        int x = (t >= o) ? ts[t - o] : 0;
        __syncthreads();
        ts[t] += x;
        __syncthreads();
    }
    int run = ts[t] - s;
#pragma unroll
    for (int j = 0; j < 8; j++) {
        int i = t * 8 + j;
        if (i < len) out[i] = run;
        run += v[j];
    }
}

__global__ void k_scan3(int* __restrict__ out, const int* __restrict__ bpre, int n) {
    int i = blockIdx.x * 256 + threadIdx.x;
    if (i < n) out[i] += bpre[i >> 10];
}

// -------------------- fp32 -> bf16 RTNE --------------------
__device__ __forceinline__ unsigned short f2bf(float f) {
    unsigned int b = __float_as_uint(f);
    b += 0x7fffu + ((b >> 16) & 1u);
    return (unsigned short)(b >> 16);
}

// -------------------- layer 0: xs = dinv * x, padded to 16 cols --------------------
__global__ void k_scale_pad(const float* __restrict__ x, const float* __restrict__ dinv,
                            float* __restrict__ xs, int n) {
    int i = blockIdx.x * 256 + threadIdx.x;
    if (i >= n) return;
    float dv = dinv[i];
    float r[16];
#pragma unroll
    for (int k = 0; k < N_FEAT; k++) r[k] = dv * x[i * N_FEAT + k];
    r[13] = r[14] = r[15] = 0.f;
    float4* o = (float4*)&xs[i * 16];
    o[0] = float4{r[0], r[1], r[2], r[3]};
    o[1] = float4{r[4], r[5], r[6], r[7]};
    o[2] = float4{r[8], r[9], r[10], r[11]};
    o[3] = float4{r[12], r[13], r[14], r[15]};
}

// -------------------- layer 0 gather on 16-wide rows (quarter-wave per dst) ----------
__global__ void k_gather13(const float* __restrict__ xs, const int* __restrict__ off,
                           const int* __restrict__ indeg, const int* __restrict__ csr,
                           const float* __restrict__ dinv, float* __restrict__ agg, int n) {
    int lane = threadIdx.x & 63;
    int q = lane >> 4, l4 = lane & 15;
    int d = blockIdx.x * 16 + (threadIdx.x >> 6) * 4 + q;
    if (d >= n) return;
    int s0 = off[d], c = indeg[d];
    float acc = xs[(size_t)d * 16 + l4];   // self term (already dinv[d]-scaled)
    int p = 0;
    for (; p + 3 < c; p += 4) {
        int sa = csr[s0 + p], sb = csr[s0 + p + 1];
        int sc_ = csr[s0 + p + 2], sd_ = csr[s0 + p + 3];
        float va = xs[(size_t)sa * 16 + l4];
        float vb = xs[(size_t)sb * 16 + l4];
        float vc = xs[(size_t)sc_ * 16 + l4];
        float vd = xs[(size_t)sd_ * 16 + l4];
        acc += (va + vb) + (vc + vd);
    }
    for (; p < c; p++) acc += xs[(size_t)csr[s0 + p] * 16 + l4];
    agg[(size_t)d * 16 + l4] = dinv[d] * acc;
}

// ---------- layer 0 GEMM: h0 = bf16(relu(agg @ W0 + b0)), K=13 ----------
__global__ void k_gemm13(const float* __restrict__ agg, const float* __restrict__ W,
                         const float* __restrict__ b, unsigned short* __restrict__ h, int n) {
    __shared__ float Ws[N_FEAT * HID];
    for (int i = threadIdx.x; i < N_FEAT * HID; i += 256) Ws[i] = W[i];
    __syncthreads();
    int i = blockIdx.x * 2 + (threadIdx.x >> 7);
    int f = threadIdx.x & 127;
    if (i >= n) return;
    float acc = b[f];
#pragma unroll
    for (int k = 0; k < N_FEAT; k++) acc += agg[(size_t)i * 16 + k] * Ws[k * HID + f];
    h[(size_t)i * HID + f] = f2bf(fmaxf(acc, 0.f));
}

// ---------- W (fp32 [K=128][N=128] row-major) -> Wt (bf16 [N][K] col-major) ----------
__global__ void k_wcast(const float* __restrict__ W, unsigned short* __restrict__ Wt) {
    int i = blockIdx.x * 256 + threadIdx.x;   // i = c*128 + k
    if (i < HID * HID) {
        int c = i >> 7, k = i & 127;
        Wt[i] = f2bf(W[k * HID + c]);
    }
}

// ---------- MFMA GEMM: ubf = bf16( dinv * (X @ W) ), X bf16 [n][128], Wt bf16 [128][128] ----------
// block = 256 thr = 4 waves; wave handles 4 node-tiles of 16 (64 nodes); no LDS.
__global__ __launch_bounds__(256) void k_mfma128(const unsigned short* __restrict__ X,
                                                 const unsigned short* __restrict__ Wt,
                                                 const float* __restrict__ dinv,
                                                 unsigned short* __restrict__ ubf, int n) {
    int t = threadIdx.x;
    int wave = t >> 6, lane = t & 63;
    int lrow = lane & 15;          // A row within tile / D col within col-tile
    int lk8 = (lane >> 4) * 8;     // k-chunk base within 32-wide K step
    int tile0 = blockIdx.x * 16 + wave * 4;   // first of 4 node-tiles for this wave

    f32x4 acc[4][8];
#pragma unroll
    for (int nt = 0; nt < 4; nt++)
#pragma unroll
        for (int ct = 0; ct < 8; ct++) acc[nt][ct] = f32x4{0.f, 0.f, 0.f, 0.f};

#pragma unroll
    for (int s = 0; s < 4; s++) {               // K steps of 32
        bf16x8 bfr[8];
#pragma unroll
        for (int ct = 0; ct < 8; ct++) {        // B frags: Wt[col][s*32+lk8 ..+8]
            int col = ct * 16 + lrow;
            bfr[ct] = *(const bf16x8*)&Wt[col * HID + s * 32 + lk8];
        }
#pragma unroll
        for (int nt = 0; nt < 4; nt++) {
            int row = min((tile0 + nt) * 16 + lrow, n - 1);
            bf16x8 afr = *(const bf16x8*)&X[(size_t)row * HID + s * 32 + lk8];
#pragma unroll
            for (int ct = 0; ct < 8; ct++)
                acc[nt][ct] = __builtin_amdgcn_mfma_f32_16x16x32_bf16(afr, bfr[ct], acc[nt][ct], 0, 0, 0);
        }
    }

    // D layout: col = lane&15 (within col-tile), row = (lane>>4)*4 + r
#pragma unroll
    for (int nt = 0; nt < 4; nt++) {
        int rbase = (tile0 + nt) * 16 + (lane >> 4) * 4;
#pragma unroll
        for (int r = 0; r < 4; r++) {
            int row = rbase + r;
            if (row < n) {
                float dv = dinv[row];
#pragma unroll
                for (int ct = 0; ct < 8; ct++)
                    ubf[(size_t)row * HID + ct * 16 + lrow] = f2bf(dv * acc[nt][ct][r]);
            }
        }
    }
}

// ---- gather over bf16 rows: half-wave per dst, 8-deep independent load pipeline ----
// outBf16=1: store bf16 row (feeds next MFMA GEMM); outBf16=0: store fp32 (feeds pool)
__global__ void k_gather128(const unsigned int* __restrict__ ubf, const int* __restrict__ off,
                            const int* __restrict__ indeg, const int* __restrict__ csr,
                            const float* __restrict__ dinv, const float* __restrict__ bias,
                            float* __restrict__ yf, unsigned short* __restrict__ yh,
                            int n, int relu, int outBf16) {
    int wv = threadIdx.x >> 6;
    int lane = threadIdx.x & 63;
    int half = lane >> 5, l2 = lane & 31;
    int d = blockIdx.x * 8 + wv * 2 + half;   // 8 nodes per 256-thread block
    if (d >= n) return;
    int s0 = off[d], c = indeg[d];
    const uint2* U = (const uint2*)ubf;   // one row = 32 uint2 (128 bf16)

    // self term
    uint2 sv = U[(size_t)d * 32 + l2];
    float a0 = __uint_as_float(sv.x << 16);
    float a1 = __uint_as_float(sv.x & 0xffff0000u);
    float a2 = __uint_as_float(sv.y << 16);
    float a3 = __uint_as_float(sv.y & 0xffff0000u);

    int p = 0;
    for (; p + 7 < c; p += 8) {        // 8 independent index+row chains in flight
        int s_[8];
#pragma unroll
        for (int j = 0; j < 8; j++) s_[j] = csr[s0 + p + j];
        uint2 v[8];
#pragma unroll
        for (int j = 0; j < 8; j++) v[j] = U[(size_t)s_[j] * 32 + l2];
#pragma unroll
        for (int j = 0; j < 8; j++) {
            a0 += __uint_as_float(v[j].x << 16);
            a1 += __uint_as_float(v[j].x & 0xffff0000u);
            a2 += __uint_as_float(v[j].y << 16);
            a3 += __uint_as_float(v[j].y & 0xffff0000u);
        }
    }
    if (p + 3 < c) {                   // 4-deep step
        int s_[4];
#pragma unroll
        for (int j = 0; j < 4; j++) s_[j] = csr[s0 + p + j];
        uint2 v[4];
#pragma unroll
        for (int j = 0; j < 4; j++) v[j] = U[(size_t)s_[j] * 32 + l2];
#pragma unroll
        for (int j = 0; j < 4; j++) {
            a0 += __uint_as_float(v[j].x << 16);
            a1 += __uint_as_float(v[j].x & 0xffff0000u);
            a2 += __uint_as_float(v[j].y << 16);
            a3 += __uint_as_float(v[j].y & 0xffff0000u);
        }
        p += 4;
    }
    for (; p < c; p++) {
        int s = csr[s0 + p];
        uint2 v = U[(size_t)s * 32 + l2];
        a0 += __uint_as_float(v.x << 16);
        a1 += __uint_as_float(v.x & 0xffff0000u);
        a2 += __uint_as_float(v.y << 16);
        a3 += __uint_as_float(v.y & 0xffff0000u);
    }

    float dv = dinv[d];
    float4 bb = *(const float4*)&bias[l2 * 4];
    float4 r = {dv * a0 + bb.x, dv * a1 + bb.y, dv * a2 + bb.z, dv * a3 + bb.w};
    if (relu) {
        r.x = fmaxf(r.x, 0.f); r.y = fmaxf(r.y, 0.f);
        r.z = fmaxf(r.z, 0.f); r.w = fmaxf(r.w, 0.f);
    }
    if (outBf16) {
        ushort4 h = {f2bf(r.x), f2bf(r.y), f2bf(r.z), f2bf(r.w)};
        *(ushort4*)&yh[(size_t)d * HID + l2 * 4] = h;
    } else {
        *(float4*)&yf[(size_t)d * HID + l2 * 4] = r;
    }
}

// -------------------- pooling --------------------
__global__ void k_cnt(const int* __restrict__ batch, int* __restrict__ cnt, int n) {
    int i = blockIdx.x * 256 + threadIdx.x;
    if (i < n) atomicAdd(&cnt[batch[i]], 1);
}

__global__ void k_pool(const float* __restrict__ h, const int* __restrict__ goff,
                       const int* __restrict__ cnt, float* __restrict__ pooledm) {
    int g = blockIdx.x;
    int t = threadIdx.x;   // 128
    int s = goff[g], c = cnt[g];
    float acc = 0.f;
    for (int i = s; i < s + c; i++) acc += h[(size_t)i * HID + t];
    pooledm[g * HID + t] = acc / (float)max(c, 1);
}

// -------------------- MLP head --------------------
__global__ void k_fc0(const float* __restrict__ in, const float* __restrict__ W,
                      const float* __restrict__ b, float* __restrict__ out) {
    __shared__ float row[128];
    int g = blockIdx.x, t = threadIdx.x;   // 256 threads
    if (t < 128) row[t] = in[g * 128 + t];
    __syncthreads();
    float acc = 0.f;
#pragma unroll 8
    for (int k = 0; k < 128; k++) acc += row[k] * W[k * 256 + t];
    acc += b[t];
    out[g * 256 + t] = fmaxf(acc, 0.f);
}

__global__ void k_fc1(const float* __restrict__ in, const float* __restrict__ W,
                      const float* __restrict__ b, float* __restrict__ out) {
    __shared__ float row[256];
    int g = blockIdx.x, t = threadIdx.x;   // 128 threads
    row[t] = in[g * 256 + t];
    row[t + 128] = in[g * 256 + t + 128];
    __syncthreads();
    float acc = 0.f;
#pragma unroll 8
    for (int k = 0; k < 256; k++) acc += row[k] * W[k * 128 + t];
    acc += b[t];
    out[g * 128 + t] = fmaxf(acc, 0.f);
}

__global__ void k_fco(const float* __restrict__ in, const float* __restrict__ Wo,
                      const float* __restrict__ bo, float* __restrict__ out) {
    int g = blockIdx.x, t = threadIdx.x;   // 64 threads = 1 wave
    float acc = in[g * 128 + t] * Wo[t] + in[g * 128 + 64 + t] * Wo[64 + t];
    for (int s = 32; s > 0; s >>= 1) acc += __shfl_down(acc, s);
    if (t == 0) out[g] = acc + bo[0];
}

// -------------------- launch --------------------
extern "C" void kernel_launch(void* const* d_in, const int* in_sizes, int n_in,
                              void* d_out, int out_size, void* d_ws, size_t ws_size,
                              hipStream_t stream) {
    const float* x   = (const float*)d_in[0];
    const int* ei    = (const int*)d_in[1];
    const int* src   = ei;
    const int* dst   = ei + N_EDGES;
    const int* batch = (const int*)d_in[2];
    const float* W0 = (const float*)d_in[3];  const float* b0 = (const float*)d_in[4];
    const float* W1 = (const float*)d_in[5];  const float* b1 = (const float*)d_in[6];
    const float* W2 = (const float*)d_in[7];  const float* b2 = (const float*)d_in[8];
    const float* Wf0 = (const float*)d_in[9];  const float* bf0 = (const float*)d_in[10];
    const float* Wf1 = (const float*)d_in[11]; const float* bf1 = (const float*)d_in[12];
    const float* Wo = (const float*)d_in[13];  const float* bo = (const float*)d_in[14];
    float* out = (float*)d_out;

    char* w = (char*)d_ws;
    size_t o = 0;
    auto take = [&](size_t bytes) -> char* {
        char* p = w + o;
        o += (bytes + 255) & ~(size_t)255;
        return p;
    };
    int* indeg    = (int*)take((size_t)N_NODES * 4);
    int* off      = (int*)take((size_t)N_NODES * 4);
    int* counts   = (int*)take((size_t)N2 * 4);
    int* countsT  = (int*)take((size_t)N2 * 4);
    int* scT      = (int*)take((size_t)N2 * 4);
    int* bsum     = (int*)take(256 * 4);
    int* bpre     = (int*)take(256 * 4);
    int* csr      = (int*)take((size_t)N_EDGES * 4);
    float* dinv   = (float*)take((size_t)N_NODES * 4);
    int* cnt      = (int*)take((size_t)N_GRAPHS * 4);
    int* goff     = (int*)take((size_t)N_GRAPHS * 4);
    float* bufA   = (float*)take((size_t)N_NODES * HID * 4);    // pool input (fp32)
    float* xs     = (float*)take((size_t)N_NODES * 16 * 4);
    float* agg    = (float*)take((size_t)N_NODES * 16 * 4);
    unsigned short* hbf0 = (unsigned short*)take((size_t)N_NODES * HID * 2);
    unsigned short* ubf  = (unsigned short*)take((size_t)N_NODES * HID * 2);
    unsigned short* Wt1  = (unsigned short*)take((size_t)HID * HID * 2);
    unsigned short* Wt2  = (unsigned short*)take((size_t)HID * HID * 2);
    float* pooledm= (float*)take((size_t)N_GRAPHS * HID * 4);
    float* fc0    = (float*)take((size_t)N_GRAPHS * 256 * 4);
    float* fc1    = (float*)take((size_t)N_GRAPHS * HID * 4);
    // bstore (6.4MB) aliases ubf (25.6MB): bstore dead after k_bfill; ubf written later
    unsigned int* bstore = (unsigned int*)ubf;
    // hbf1 aliases bufA: hbf1 (layer1 h, bf16) dead after layer2 MFMA; bufA written by layer2 gather
    unsigned short* hbf1 = (unsigned short*)bufA;

    hipMemsetAsync(cnt, 0, (size_t)N_GRAPHS * 4, stream);

    // ---- topology: contention-free counting sort by dst bucket ----
    k_hist1<<<NBLK, 256, 0, stream>>>(dst, counts, N_EDGES);
    k_transp<<<(N2 + 255) / 256, 256, 0, stream>>>(counts, countsT);
    int nb2 = (N2 + 1023) / 1024;
    k_scan1<<<nb2, 256, 0, stream>>>(countsT, scT, bsum, N2);
    k_scan_block<<<1, 256, 0, stream>>>(bsum, bpre, nb2);
    k_scan3<<<(N2 + 255) / 256, 256, 0, stream>>>(scT, bpre, N2);
    k_scatter<<<NBLK, 256, 0, stream>>>(src, dst, scT, bstore, N_EDGES);
    k_bhist<<<NB, 256, 0, stream>>>(bstore, scT, indeg, dinv, N_NODES, N_EDGES);
    int nb1 = (N_NODES + 1023) / 1024;
    k_scan1<<<nb1, 256, 0, stream>>>(indeg, off, bsum, N_NODES);
    k_scan_block<<<1, 256, 0, stream>>>(bsum, bpre, nb1);
    k_scan3<<<(N_NODES + 255) / 256, 256, 0, stream>>>(off, bpre, N_NODES);
    k_bfill<<<NB, 256, 0, stream>>>(bstore, scT, off, csr, N_NODES, N_EDGES);
    k_cnt<<<(N_NODES + 255) / 256, 256, 0, stream>>>(batch, cnt, N_NODES);
    k_scan_block<<<1, 256, 0, stream>>>(cnt, goff, N_GRAPHS);

    // weight prep for MFMA layers
    k_wcast<<<(HID * HID + 255) / 256, 256, 0, stream>>>(W1, Wt1);
    k_wcast<<<(HID * HID + 255) / 256, 256, 0, stream>>>(W2, Wt2);

    // layer 0: aggregate 13-wide first, then GEMM -> bf16 h0
    k_scale_pad<<<(N_NODES + 255) / 256, 256, 0, stream>>>(x, dinv, xs, N_NODES);
    k_gather13<<<(N_NODES + 15) / 16, 256, 0, stream>>>(xs, off, indeg, csr, dinv, agg, N_NODES);
    k_gemm13<<<(N_NODES + 1) / 2, 256, 0, stream>>>(agg, W0, b0, hbf0, N_NODES);
    // layer 1: MFMA GEMM + gather (bf16 out)
    k_mfma128<<<(N_NODES + 255) / 256, 256, 0, stream>>>(hbf0, Wt1, dinv, ubf, N_NODES);
    k_gather128<<<(N_NODES + 7) / 8, 256, 0, stream>>>((const unsigned int*)ubf, off, indeg, csr, dinv, b1, nullptr, hbf1, N_NODES, 1, 1);
    // layer 2: MFMA GEMM + gather (fp32 out, no relu)
    k_mfma128<<<(N_NODES + 255) / 256, 256, 0, stream>>>(hbf1, Wt2, dinv, ubf, N_NODES);
    k_gather128<<<(N_NODES + 7) / 8, 256, 0, stream>>>((const unsigned int*)ubf, off, indeg, csr, dinv, b2, bufA, nullptr, N_NODES, 0, 0);

    // pool + MLP head
    k_pool<<<N_GRAPHS, 128, 0, stream>>>(bufA, goff, cnt, pooledm);
    k_fc0<<<N_GRAPHS, 256, 0, stream>>>(pooledm, Wf0, bf0, fc0);
    k_fc1<<<N_GRAPHS, 128, 0, stream>>>(fc0, Wf1, bf1, fc1);
    k_fco<<<N_GRAPHS, 64, 0, stream>>>(fc1, Wo, bo, out);
}

// Round 8
// 361.417 us; speedup vs baseline: 2.3426x; 1.1913x over previous
//
#include <hip/hip_runtime.h>
#include <hip/hip_bf16.h>

#define N_NODES  100000
#define N_EDGES  1600000
#define N_GRAPHS 2000
#define N_FEAT   13
#define HID      128
#define NB       ((N_NODES + 127) / 128)   // 782 buckets of 128 nodes
#define NBLK     128                        // edge-partition blocks for the sort
#define N2       (NB * NBLK)                // 100096 (bucket,block) windows

typedef __attribute__((ext_vector_type(8))) short bf16x8;   // 8 bf16 = 4 VGPRs
typedef __attribute__((ext_vector_type(4))) float f32x4;

// ============ contention-free counting sort of edges by dst bucket ============
__global__ void k_hist1(const int* __restrict__ dst, int* __restrict__ counts, int E) {
    __shared__ int hist[NB];
    int k = blockIdx.x, t = threadIdx.x;
    for (int b = t; b < NB; b += 256) hist[b] = 0;
    __syncthreads();
    int epb = (E + NBLK - 1) / NBLK;
    int base = k * epb, lim = min(base + epb, E);
    for (int i = base + t; i < lim; i += 256) atomicAdd(&hist[dst[i] >> 7], 1);
    __syncthreads();
    for (int b = t; b < NB; b += 256) counts[k * NB + b] = hist[b];
}

__global__ void k_transp(const int* __restrict__ counts, int* __restrict__ countsT) {
    int i = blockIdx.x * 256 + threadIdx.x;   // i = b*NBLK + k
    if (i < N2) countsT[i] = counts[(i & (NBLK - 1)) * NB + (i >> 7)];
}

__global__ void k_scatter(const int* __restrict__ src, const int* __restrict__ dst,
                          const int* __restrict__ scT, unsigned int* __restrict__ bstore, int E) {
    __shared__ int cnt[NB];
    int k = blockIdx.x, t = threadIdx.x;
    for (int b = t; b < NB; b += 256) cnt[b] = 0;
    __syncthreads();
    int epb = (E + NBLK - 1) / NBLK;
    int base = k * epb, lim = min(base + epb, E);
    for (int i = base + t; i < lim; i += 256) {
        int d = dst[i];
        int b = d >> 7;
        int r = atomicAdd(&cnt[b], 1);    // LDS rank within (bucket, block) window
        bstore[scT[b * NBLK + k] + r] = ((unsigned int)src[i] << 7) | (unsigned int)(d & 127);
    }
}

// per-bucket node histogram -> indeg + dinv + xs (= dinv * x, padded to 16)
__global__ void k_bhistx(const unsigned int* __restrict__ bstore, const int* __restrict__ scT,
                         const float* __restrict__ x, int* __restrict__ indeg,
                         float* __restrict__ dinv, float* __restrict__ xs, int n, int E) {
    __shared__ int cnt[128];
    int b = blockIdx.x, t = threadIdx.x;
    if (t < 128) cnt[t] = 0;
    __syncthreads();
    int start = scT[b * NBLK];
    int end = (b + 1 < NB) ? scT[(b + 1) * NBLK] : E;
    for (int i = start + t; i < end; i += 256) atomicAdd(&cnt[bstore[i] & 127], 1);
    __syncthreads();
    int node = b * 128 + t;
    if (t < 128 && node < n) {
        int c = cnt[t];
        indeg[node] = c;
        float dv = rsqrtf((float)(c + 1));   // +1 self loop
        dinv[node] = dv;
        float r[16];
#pragma unroll
        for (int k = 0; k < N_FEAT; k++) r[k] = dv * x[node * N_FEAT + k];
        r[13] = r[14] = r[15] = 0.f;
        float4* o = (float4*)&xs[(size_t)node * 16];
        o[0] = float4{r[0], r[1], r[2], r[3]};
        o[1] = float4{r[4], r[5], r[6], r[7]};
        o[2] = float4{r[8], r[9], r[10], r[11]};
        o[3] = float4{r[12], r[13], r[14], r[15]};
    }
}

__global__ void k_bfill(const unsigned int* __restrict__ bstore, const int* __restrict__ scT,
                        const int* __restrict__ off, int* __restrict__ csr, int n, int E) {
    __shared__ int cur[128];
    __shared__ int loff[128];
    int b = blockIdx.x, t = threadIdx.x;
    if (t < 128) {
        cur[t] = 0;
        int node = b * 128 + t;
        loff[t] = (node < n) ? off[node] : 0;
    }
    __syncthreads();
    int start = scT[b * NBLK];
    int end = (b + 1 < NB) ? scT[(b + 1) * NBLK] : E;
    for (int i = start + t; i < end; i += 256) {
        unsigned int e = bstore[i];
        int dl = e & 127;
        int p = loff[dl] + atomicAdd(&cur[dl], 1);
        csr[p] = (int)(e >> 7);
    }
}

// -------------------- scans (exclusive) --------------------
__global__ void k_scan1(const int* __restrict__ in, int* __restrict__ out,
                        int* __restrict__ bsum, int n) {
    __shared__ int ts[256];
    int t = threadIdx.x;
    int base = blockIdx.x * 1024 + t * 4;
    int v0 = (base + 0 < n) ? in[base + 0] : 0;
    int v1 = (base + 1 < n) ? in[base + 1] : 0;
    int v2 = (base + 2 < n) ? in[base + 2] : 0;
    int v3 = (base + 3 < n) ? in[base + 3] : 0;
    int s = v0 + v1 + v2 + v3;
    ts[t] = s;
    __syncthreads();
    for (int o = 1; o < 256; o <<= 1) {
        int x = (t >= o) ? ts[t - o] : 0;
        __syncthreads();
        ts[t] += x;
        __syncthreads();
    }
    if (t == 255) bsum[blockIdx.x] = ts[255];
    int run = ts[t] - s;
    if (base + 0 < n) out[base + 0] = run; run += v0;
    if (base + 1 < n) out[base + 1] = run; run += v1;
    if (base + 2 < n) out[base + 2] = run; run += v2;
    if (base + 3 < n) out[base + 3] = run;
}

__global__ void k_scan_block(const int* __restrict__ in, int* __restrict__ out, int len) {
    __shared__ int ts[256];
    int t = threadIdx.x;
    int v[8];
    int s = 0;
#pragma unroll
    for (int j = 0; j < 8; j++) {
        int i = t * 8 + j;
        v[j] = (i < len) ? in[i] : 0;
        s += v[j];
    }
    ts[t] = s;
    __syncthreads();
    for (int o = 1; o < 256; o <<= 1) {
        int x = (t >= o) ? ts[t - o] : 0;
        __syncthreads();
        ts[t] += x;
        __syncthreads();
    }
    int run = ts[t] - s;
#pragma unroll
    for (int j = 0; j < 8; j++) {
        int i = t * 8 + j;
        if (i < len) out[i] = run;
        run += v[j];
    }
}

__global__ void k_scan3(int* __restrict__ out, const int* __restrict__ bpre, int n) {
    int i = blockIdx.x * 256 + threadIdx.x;
    if (i < n) out[i] += bpre[i >> 10];
}

// -------------------- fp32 -> bf16 RTNE --------------------
__device__ __forceinline__ unsigned short f2bf(float f) {
    unsigned int b = __float_as_uint(f);
    b += 0x7fffu + ((b >> 16) & 1u);
    return (unsigned short)(b >> 16);
}

// ---- layer 0 fused: gather (16-wide, quarter-wave per dst, 8-deep) + GEMM K=13 ----
__global__ __launch_bounds__(256) void k_gf13(const float* __restrict__ xs,
                                              const int* __restrict__ off,
                                              const int* __restrict__ indeg,
                                              const int* __restrict__ csr,
                                              const float* __restrict__ dinv,
                                              const float* __restrict__ W,
                                              const float* __restrict__ b,
                                              unsigned short* __restrict__ h, int n) {
    __shared__ float Ws[N_FEAT * HID];
    __shared__ float aggs[16][16];
    __shared__ float bs[HID];
    int t = threadIdx.x;
    for (int i = t; i < N_FEAT * HID; i += 256) Ws[i] = W[i];
    if (t < HID) bs[t] = b[t];
    int lane = t & 63;
    int q = lane >> 4, l4 = lane & 15;
    int nl_g = (t >> 6) * 4 + q;     // node slot 0..15 within block
    int nb = blockIdx.x * 16;
    int d = nb + nl_g;
    if (d < n) {
        int s0 = off[d], c = indeg[d];
        float acc = xs[(size_t)d * 16 + l4];   // self term (already dinv[d]-scaled)
        int p = 0;
        for (; p + 7 < c; p += 8) {            // 8 independent chains in flight
            int s_[8];
#pragma unroll
            for (int j = 0; j < 8; j++) s_[j] = csr[s0 + p + j];
            float v[8];
#pragma unroll
            for (int j = 0; j < 8; j++) v[j] = xs[(size_t)s_[j] * 16 + l4];
#pragma unroll
            for (int j = 0; j < 8; j++) acc += v[j];
        }
        for (; p < c; p++) acc += xs[(size_t)csr[s0 + p] * 16 + l4];
        aggs[nl_g][l4] = dinv[d] * acc;
    }
    __syncthreads();
    // h0 = bf16(relu(aggs @ W0 + b0)); thread owns one feature column, 8 nodes
    int f = t & 127;
    int g0 = t >> 7;                 // 0 or 1
    float wreg[N_FEAT];
#pragma unroll
    for (int k = 0; k < N_FEAT; k++) wreg[k] = Ws[k * HID + f];
#pragma unroll
    for (int j = 0; j < 8; j++) {
        int nl = g0 + j * 2;
        int dd = nb + nl;
        if (dd < n) {
            float acc = bs[f];
#pragma unroll
            for (int k = 0; k < N_FEAT; k++) acc += aggs[nl][k] * wreg[k];
            h[(size_t)dd * HID + f] = f2bf(fmaxf(acc, 0.f));
        }
    }
}

// ---------- W1,W2 (fp32 [K][N] row-major) -> Wt (bf16 [N][K]) in one launch ----------
__global__ void k_wcast2(const float* __restrict__ W1, const float* __restrict__ W2,
                         unsigned short* __restrict__ Wt1, unsigned short* __restrict__ Wt2) {
    int i = blockIdx.x * 256 + threadIdx.x;
    if (i < HID * HID) {
        int c = i >> 7, k = i & 127;
        Wt1[i] = f2bf(W1[k * HID + c]);
        Wt2[i] = f2bf(W2[k * HID + c]);
    }
}

// ---------- MFMA GEMM: ubf = bf16( dinv * (X @ W) ), X bf16 [n][128], Wt bf16 [128][128] ----------
__global__ __launch_bounds__(256) void k_mfma128(const unsigned short* __restrict__ X,
                                                 const unsigned short* __restrict__ Wt,
                                                 const float* __restrict__ dinv,
                                                 unsigned short* __restrict__ ubf, int n) {
    int t = threadIdx.x;
    int wave = t >> 6, lane = t & 63;
    int lrow = lane & 15;          // A row within tile / D col within col-tile
    int lk8 = (lane >> 4) * 8;     // k-chunk base within 32-wide K step
    int tile0 = blockIdx.x * 16 + wave * 4;   // first of 4 node-tiles for this wave

    f32x4 acc[4][8];
#pragma unroll
    for (int nt = 0; nt < 4; nt++)
#pragma unroll
        for (int ct = 0; ct < 8; ct++) acc[nt][ct] = f32x4{0.f, 0.f, 0.f, 0.f};

#pragma unroll
    for (int s = 0; s < 4; s++) {               // K steps of 32
        bf16x8 bfr[8];
#pragma unroll
        for (int ct = 0; ct < 8; ct++) {        // B frags: Wt[col][s*32+lk8 ..+8]
            int col = ct * 16 + lrow;
            bfr[ct] = *(const bf16x8*)&Wt[col * HID + s * 32 + lk8];
        }
#pragma unroll
        for (int nt = 0; nt < 4; nt++) {
            int row = min((tile0 + nt) * 16 + lrow, n - 1);
            bf16x8 afr = *(const bf16x8*)&X[(size_t)row * HID + s * 32 + lk8];
#pragma unroll
            for (int ct = 0; ct < 8; ct++)
                acc[nt][ct] = __builtin_amdgcn_mfma_f32_16x16x32_bf16(afr, bfr[ct], acc[nt][ct], 0, 0, 0);
        }
    }

    // D layout: col = lane&15 (within col-tile), row = (lane>>4)*4 + r
#pragma unroll
    for (int nt = 0; nt < 4; nt++) {
        int rbase = (tile0 + nt) * 16 + (lane >> 4) * 4;
#pragma unroll
        for (int r = 0; r < 4; r++) {
            int row = rbase + r;
            if (row < n) {
                float dv = dinv[row];
#pragma unroll
                for (int ct = 0; ct < 8; ct++)
                    ubf[(size_t)row * HID + ct * 16 + lrow] = f2bf(dv * acc[nt][ct][r]);
            }
        }
    }
}

// ---- layer-1 gather over bf16 rows: half-wave per dst, 8-deep pipeline, bf16 out ----
__global__ void k_gather128(const unsigned int* __restrict__ ubf, const int* __restrict__ off,
                            const int* __restrict__ indeg, const int* __restrict__ csr,
                            const float* __restrict__ dinv, const float* __restrict__ bias,
                            unsigned short* __restrict__ yh, int n) {
    int wv = threadIdx.x >> 6;
    int lane = threadIdx.x & 63;
    int half = lane >> 5, l2 = lane & 31;
    int d = blockIdx.x * 8 + wv * 2 + half;   // 8 nodes per 256-thread block
    if (d >= n) return;
    int s0 = off[d], c = indeg[d];
    const uint2* U = (const uint2*)ubf;   // one row = 32 uint2 (128 bf16)

    uint2 sv = U[(size_t)d * 32 + l2];    // self term
    float a0 = __uint_as_float(sv.x << 16);
    float a1 = __uint_as_float(sv.x & 0xffff0000u);
    float a2 = __uint_as_float(sv.y << 16);
    float a3 = __uint_as_float(sv.y & 0xffff0000u);

    int p = 0;
    for (; p + 7 < c; p += 8) {
        int s_[8];
#pragma unroll
        for (int j = 0; j < 8; j++) s_[j] = csr[s0 + p + j];
        uint2 v[8];
#pragma unroll
        for (int j = 0; j < 8; j++) v[j] = U[(size_t)s_[j] * 32 + l2];
#pragma unroll
        for (int j = 0; j < 8; j++) {
            a0 += __uint_as_float(v[j].x << 16);
            a1 += __uint_as_float(v[j].x & 0xffff0000u);
            a2 += __uint_as_float(v[j].y << 16);
            a3 += __uint_as_float(v[j].y & 0xffff0000u);
        }
    }
    if (p + 3 < c) {
        int s_[4];
#pragma unroll
        for (int j = 0; j < 4; j++) s_[j] = csr[s0 + p + j];
        uint2 v[4];
#pragma unroll
        for (int j = 0; j < 4; j++) v[j] = U[(size_t)s_[j] * 32 + l2];
#pragma unroll
        for (int j = 0; j < 4; j++) {
            a0 += __uint_as_float(v[j].x << 16);
            a1 += __uint_as_float(v[j].x & 0xffff0000u);
            a2 += __uint_as_float(v[j].y << 16);
            a3 += __uint_as_float(v[j].y & 0xffff0000u);
        }
        p += 4;
    }
    for (; p < c; p++) {
        int s = csr[s0 + p];
        uint2 v = U[(size_t)s * 32 + l2];
        a0 += __uint_as_float(v.x << 16);
        a1 += __uint_as_float(v.x & 0xffff0000u);
        a2 += __uint_as_float(v.y << 16);
        a3 += __uint_as_float(v.y & 0xffff0000u);
    }

    float dv = dinv[d];
    float4 bb = *(const float4*)&bias[l2 * 4];
    float4 r = {fmaxf(dv * a0 + bb.x, 0.f), fmaxf(dv * a1 + bb.y, 0.f),
                fmaxf(dv * a2 + bb.z, 0.f), fmaxf(dv * a3 + bb.w, 0.f)};
    ushort4 hh = {f2bf(r.x), f2bf(r.y), f2bf(r.z), f2bf(r.w)};
    *(ushort4*)&yh[(size_t)d * HID + l2 * 4] = hh;
}

// ---- layer-2 gather fused with mean-pool accumulation (batch sorted -> runs) ----
__global__ void k_gather128p(const unsigned int* __restrict__ ubf, const int* __restrict__ off,
                             const int* __restrict__ indeg, const int* __restrict__ csr,
                             const float* __restrict__ dinv, const float* __restrict__ bias,
                             const int* __restrict__ batch, float* __restrict__ pooledm, int n) {
    __shared__ float part[8][128];
    __shared__ int bid[8];
    int wv = threadIdx.x >> 6;
    int lane = threadIdx.x & 63;
    int half = lane >> 5, l2 = lane & 31;
    int hw = wv * 2 + half;
    int d = blockIdx.x * 8 + hw;
    const uint2* U = (const uint2*)ubf;
    if (d < n) {
        int s0 = off[d], c = indeg[d];
        uint2 sv = U[(size_t)d * 32 + l2];
        float a0 = __uint_as_float(sv.x << 16);
        float a1 = __uint_as_float(sv.x & 0xffff0000u);
        float a2 = __uint_as_float(sv.y << 16);
        float a3 = __uint_as_float(sv.y & 0xffff0000u);
        int p = 0;
        for (; p + 7 < c; p += 8) {
            int s_[8];
#pragma unroll
            for (int j = 0; j < 8; j++) s_[j] = csr[s0 + p + j];
            uint2 v[8];
#pragma unroll
            for (int j = 0; j < 8; j++) v[j] = U[(size_t)s_[j] * 32 + l2];
#pragma unroll
            for (int j = 0; j < 8; j++) {
                a0 += __uint_as_float(v[j].x << 16);
                a1 += __uint_as_float(v[j].x & 0xffff0000u);
                a2 += __uint_as_float(v[j].y << 16);
                a3 += __uint_as_float(v[j].y & 0xffff0000u);
            }
        }
        if (p + 3 < c) {
            int s_[4];
#pragma unroll
            for (int j = 0; j < 4; j++) s_[j] = csr[s0 + p + j];
            uint2 v[4];
#pragma unroll
            for (int j = 0; j < 4; j++) v[j] = U[(size_t)s_[j] * 32 + l2];
#pragma unroll
            for (int j = 0; j < 4; j++) {
                a0 += __uint_as_float(v[j].x << 16);
                a1 += __uint_as_float(v[j].x & 0xffff0000u);
                a2 += __uint_as_float(v[j].y << 16);
                a3 += __uint_as_float(v[j].y & 0xffff0000u);
            }
            p += 4;
        }
        for (; p < c; p++) {
            int s = csr[s0 + p];
            uint2 v = U[(size_t)s * 32 + l2];
            a0 += __uint_as_float(v.x << 16);
            a1 += __uint_as_float(v.x & 0xffff0000u);
            a2 += __uint_as_float(v.y << 16);
            a3 += __uint_as_float(v.y & 0xffff0000u);
        }
        float dv = dinv[d];
        float4 bb = *(const float4*)&bias[l2 * 4];
        float4 r = {dv * a0 + bb.x, dv * a1 + bb.y, dv * a2 + bb.z, dv * a3 + bb.w};
        *(float4*)&part[hw][l2 * 4] = r;
        if (l2 == 0) bid[hw] = batch[d];
    } else {
        if (l2 == 0) bid[hw] = -1;
    }
    __syncthreads();
    if (threadIdx.x < 128) {      // per-feature run reduction over the 8 nodes
        int f = threadIdx.x;
        float acc = 0.f;
        int g = -1;
        for (int j = 0; j < 8; j++) {
            int bj = bid[j];
            if (bj < 0) break;    // tail block: invalid nodes are trailing
            if (bj != g) {
                if (g >= 0) atomicAdd(&pooledm[g * HID + f], acc);
                g = bj; acc = 0.f;
            }
            acc += part[j][f];
        }
        if (g >= 0) atomicAdd(&pooledm[g * HID + f], acc);
    }
}

// -------------------- graph node counts --------------------
__global__ void k_cnt(const int* __restrict__ batch, int* __restrict__ cnt, int n) {
    int i = blockIdx.x * 256 + threadIdx.x;
    if (i < n) atomicAdd(&cnt[batch[i]], 1);
}

// -------------------- MLP head --------------------
__global__ void k_fc0(const float* __restrict__ in, const int* __restrict__ cnt,
                      const float* __restrict__ W, const float* __restrict__ b,
                      float* __restrict__ out) {
    __shared__ float row[128];
    int g = blockIdx.x, t = threadIdx.x;   // 256 threads
    if (t < 128) row[t] = in[g * 128 + t] * (1.f / (float)max(cnt[g], 1));
    __syncthreads();
    float acc = 0.f;
#pragma unroll 8
    for (int k = 0; k < 128; k++) acc += row[k] * W[k * 256 + t];
    acc += b[t];
    out[g * 256 + t] = fmaxf(acc, 0.f);
}

__global__ void k_fc1(const float* __restrict__ in, const float* __restrict__ W,
                      const float* __restrict__ b, float* __restrict__ out) {
    __shared__ float row[256];
    int g = blockIdx.x, t = threadIdx.x;   // 128 threads
    row[t] = in[g * 256 + t];
    row[t + 128] = in[g * 256 + t + 128];
    __syncthreads();
    float acc = 0.f;
#pragma unroll 8
    for (int k = 0; k < 256; k++) acc += row[k] * W[k * 128 + t];
    acc += b[t];
    out[g * 128 + t] = fmaxf(acc, 0.f);
}

__global__ void k_fco(const float* __restrict__ in, const float* __restrict__ Wo,
                      const float* __restrict__ bo, float* __restrict__ out) {
    int g = blockIdx.x, t = threadIdx.x;   // 64 threads = 1 wave
    float acc = in[g * 128 + t] * Wo[t] + in[g * 128 + 64 + t] * Wo[64 + t];
    for (int s = 32; s > 0; s >>= 1) acc += __shfl_down(acc, s);
    if (t == 0) out[g] = acc + bo[0];
}

// -------------------- launch --------------------
extern "C" void kernel_launch(void* const* d_in, const int* in_sizes, int n_in,
                              void* d_out, int out_size, void* d_ws, size_t ws_size,
                              hipStream_t stream) {
    const float* x   = (const float*)d_in[0];
    const int* ei    = (const int*)d_in[1];
    const int* src   = ei;
    const int* dst   = ei + N_EDGES;
    const int* batch = (const int*)d_in[2];
    const float* W0 = (const float*)d_in[3];  const float* b0 = (const float*)d_in[4];
    const float* W1 = (const float*)d_in[5];  const float* b1 = (const float*)d_in[6];
    const float* W2 = (const float*)d_in[7];  const float* b2 = (const float*)d_in[8];
    const float* Wf0 = (const float*)d_in[9];  const float* bf0 = (const float*)d_in[10];
    const float* Wf1 = (const float*)d_in[11]; const float* bf1 = (const float*)d_in[12];
    const float* Wo = (const float*)d_in[13];  const float* bo = (const float*)d_in[14];
    float* out = (float*)d_out;

    char* w = (char*)d_ws;
    size_t o = 0;
    auto take = [&](size_t bytes) -> char* {
        char* p = w + o;
        o += (bytes + 255) & ~(size_t)255;
        return p;
    };
    int* indeg    = (int*)take((size_t)N_NODES * 4);
    int* off      = (int*)take((size_t)N_NODES * 4);
    int* counts   = (int*)take((size_t)N2 * 4);
    int* countsT  = (int*)take((size_t)N2 * 4);
    int* scT      = (int*)take((size_t)N2 * 4);
    int* bsum     = (int*)take(256 * 4);
    int* bpre     = (int*)take(256 * 4);
    int* csr      = (int*)take((size_t)N_EDGES * 4);
    float* dinv   = (float*)take((size_t)N_NODES * 4);
    int* cnt      = (int*)take((size_t)N_GRAPHS * 4);
    float* xs     = (float*)take((size_t)N_NODES * 16 * 4);
    unsigned short* hbf0 = (unsigned short*)take((size_t)N_NODES * HID * 2);
    unsigned short* hbf1 = (unsigned short*)take((size_t)N_NODES * HID * 2);
    unsigned short* ubf  = (unsigned short*)take((size_t)N_NODES * HID * 2);
    unsigned short* Wt1  = (unsigned short*)take((size_t)HID * HID * 2);
    unsigned short* Wt2  = (unsigned short*)take((size_t)HID * HID * 2);
    float* pooledm= (float*)take((size_t)N_GRAPHS * HID * 4);
    float* fc0    = (float*)take((size_t)N_GRAPHS * 256 * 4);
    float* fc1    = (float*)take((size_t)N_GRAPHS * HID * 4);
    // bstore (6.4MB) aliases ubf (25.6MB): bstore dead after k_bfill; ubf written later
    unsigned int* bstore = (unsigned int*)ubf;

    hipMemsetAsync(cnt, 0, (size_t)N_GRAPHS * 4, stream);
    hipMemsetAsync(pooledm, 0, (size_t)N_GRAPHS * HID * 4, stream);

    // ---- topology: contention-free counting sort by dst bucket ----
    k_hist1<<<NBLK, 256, 0, stream>>>(dst, counts, N_EDGES);
    k_transp<<<(N2 + 255) / 256, 256, 0, stream>>>(counts, countsT);
    int nb2 = (N2 + 1023) / 1024;
    k_scan1<<<nb2, 256, 0, stream>>>(countsT, scT, bsum, N2);
    k_scan_block<<<1, 256, 0, stream>>>(bsum, bpre, nb2);
    k_scan3<<<(N2 + 255) / 256, 256, 0, stream>>>(scT, bpre, N2);
    k_scatter<<<NBLK, 256, 0, stream>>>(src, dst, scT, bstore, N_EDGES);
    k_bhistx<<<NB, 256, 0, stream>>>(bstore, scT, x, indeg, dinv, xs, N_NODES, N_EDGES);
    int nb1 = (N_NODES + 1023) / 1024;
    k_scan1<<<nb1, 256, 0, stream>>>(indeg, off, bsum, N_NODES);
    k_scan_block<<<1, 256, 0, stream>>>(bsum, bpre, nb1);
    k_scan3<<<(N_NODES + 255) / 256, 256, 0, stream>>>(off, bpre, N_NODES);
    k_bfill<<<NB, 256, 0, stream>>>(bstore, scT, off, csr, N_NODES, N_EDGES);
    k_cnt<<<(N_NODES + 255) / 256, 256, 0, stream>>>(batch, cnt, N_NODES);
    k_wcast2<<<(HID * HID + 255) / 256, 256, 0, stream>>>(W1, W2, Wt1, Wt2);

    // layer 0: fused gather(13-wide) + GEMM -> bf16 h0
    k_gf13<<<(N_NODES + 15) / 16, 256, 0, stream>>>(xs, off, indeg, csr, dinv, W0, b0, hbf0, N_NODES);
    // layer 1: MFMA GEMM + gather (bf16 out)
    k_mfma128<<<(N_NODES + 255) / 256, 256, 0, stream>>>(hbf0, Wt1, dinv, ubf, N_NODES);
    k_gather128<<<(N_NODES + 7) / 8, 256, 0, stream>>>((const unsigned int*)ubf, off, indeg, csr, dinv, b1, hbf1, N_NODES);
    // layer 2: MFMA GEMM + gather fused with mean-pool accumulation
    k_mfma128<<<(N_NODES + 255) / 256, 256, 0, stream>>>(hbf1, Wt2, dinv, ubf, N_NODES);
    k_gather128p<<<(N_NODES + 7) / 8, 256, 0, stream>>>((const unsigned int*)ubf, off, indeg, csr, dinv, b2, batch, pooledm, N_NODES);

    // MLP head (fc0 divides by per-graph count)
    k_fc0<<<N_GRAPHS, 256, 0, stream>>>(pooledm, cnt, Wf0, bf0, fc0);
    k_fc1<<<N_GRAPHS, 128, 0, stream>>>(fc0, Wf1, bf1, fc1);
    k_fco<<<N_GRAPHS, 64, 0, stream>>>(fc1, Wo, bo, out);
}

// Round 9
// 350.438 us; speedup vs baseline: 2.4160x; 1.0313x over previous
//
#include <hip/hip_runtime.h>
#include <hip/hip_bf16.h>

#define N_NODES  100000
#define N_EDGES  1600000
#define N_GRAPHS 2000
#define N_FEAT   13
#define HID      128
#define NB       ((N_NODES + 127) / 128)   // 782 buckets of 128 nodes
#define NBLK     128                        // edge-partition blocks for the sort
#define N2       (NB * NBLK)                // 100096 (bucket,block) windows

typedef __attribute__((ext_vector_type(8))) short bf16x8;   // 8 bf16 = 4 VGPRs
typedef __attribute__((ext_vector_type(4))) float f32x4;
typedef __attribute__((ext_vector_type(8))) unsigned short ushort8;

// ============ contention-free counting sort of edges by dst bucket ============
__global__ void k_hist1(const int* __restrict__ dst, int* __restrict__ counts, int E) {
    __shared__ int hist[NB];
    int k = blockIdx.x, t = threadIdx.x;
    for (int b = t; b < NB; b += 256) hist[b] = 0;
    __syncthreads();
    int epb = (E + NBLK - 1) / NBLK;
    int base = k * epb, lim = min(base + epb, E);
    for (int i = base + t; i < lim; i += 256) atomicAdd(&hist[dst[i] >> 7], 1);
    __syncthreads();
    for (int b = t; b < NB; b += 256) counts[k * NB + b] = hist[b];
}

__global__ void k_transp(const int* __restrict__ counts, int* __restrict__ countsT) {
    int i = blockIdx.x * 256 + threadIdx.x;   // i = b*NBLK + k
    if (i < N2) countsT[i] = counts[(i & (NBLK - 1)) * NB + (i >> 7)];
}

__global__ void k_scatter(const int* __restrict__ src, const int* __restrict__ dst,
                          const int* __restrict__ scT, unsigned int* __restrict__ bstore, int E) {
    __shared__ int cnt[NB];
    int k = blockIdx.x, t = threadIdx.x;
    for (int b = t; b < NB; b += 256) cnt[b] = 0;
    __syncthreads();
    int epb = (E + NBLK - 1) / NBLK;
    int base = k * epb, lim = min(base + epb, E);
    for (int i = base + t; i < lim; i += 256) {
        int d = dst[i];
        int b = d >> 7;
        int r = atomicAdd(&cnt[b], 1);    // LDS rank within (bucket, block) window
        bstore[scT[b * NBLK + k] + r] = ((unsigned int)src[i] << 7) | (unsigned int)(d & 127);
    }
}

// per-bucket node histogram -> indeg + dinv + xs (= dinv * x, padded to 16)
__global__ void k_bhistx(const unsigned int* __restrict__ bstore, const int* __restrict__ scT,
                         const float* __restrict__ x, int* __restrict__ indeg,
                         float* __restrict__ dinv, float* __restrict__ xs, int n, int E) {
    __shared__ int cnt[128];
    int b = blockIdx.x, t = threadIdx.x;
    if (t < 128) cnt[t] = 0;
    __syncthreads();
    int start = scT[b * NBLK];
    int end = (b + 1 < NB) ? scT[(b + 1) * NBLK] : E;
    for (int i = start + t; i < end; i += 256) atomicAdd(&cnt[bstore[i] & 127], 1);
    __syncthreads();
    int node = b * 128 + t;
    if (t < 128 && node < n) {
        int c = cnt[t];
        indeg[node] = c;
        float dv = rsqrtf((float)(c + 1));   // +1 self loop
        dinv[node] = dv;
        float r[16];
#pragma unroll
        for (int k = 0; k < N_FEAT; k++) r[k] = dv * x[node * N_FEAT + k];
        r[13] = r[14] = r[15] = 0.f;
        float4* o = (float4*)&xs[(size_t)node * 16];
        o[0] = float4{r[0], r[1], r[2], r[3]};
        o[1] = float4{r[4], r[5], r[6], r[7]};
        o[2] = float4{r[8], r[9], r[10], r[11]};
        o[3] = float4{r[12], r[13], r[14], r[15]};
    }
}

__global__ void k_bfill(const unsigned int* __restrict__ bstore, const int* __restrict__ scT,
                        const int* __restrict__ off, int* __restrict__ csr, int n, int E) {
    __shared__ int cur[128];
    __shared__ int loff[128];
    int b = blockIdx.x, t = threadIdx.x;
    if (t < 128) {
        cur[t] = 0;
        int node = b * 128 + t;
        loff[t] = (node < n) ? off[node] : 0;
    }
    __syncthreads();
    int start = scT[b * NBLK];
    int end = (b + 1 < NB) ? scT[(b + 1) * NBLK] : E;
    for (int i = start + t; i < end; i += 256) {
        unsigned int e = bstore[i];
        int dl = e & 127;
        int p = loff[dl] + atomicAdd(&cur[dl], 1);
        csr[p] = (int)(e >> 7);
    }
}

// -------------------- scans (exclusive) --------------------
__global__ void k_scan1(const int* __restrict__ in, int* __restrict__ out,
                        int* __restrict__ bsum, int n) {
    __shared__ int ts[256];
    int t = threadIdx.x;
    int base = blockIdx.x * 1024 + t * 4;
    int v0 = (base + 0 < n) ? in[base + 0] : 0;
    int v1 = (base + 1 < n) ? in[base + 1] : 0;
    int v2 = (base + 2 < n) ? in[base + 2] : 0;
    int v3 = (base + 3 < n) ? in[base + 3] : 0;
    int s = v0 + v1 + v2 + v3;
    ts[t] = s;
    __syncthreads();
    for (int o = 1; o < 256; o <<= 1) {
        int x = (t >= o) ? ts[t - o] : 0;
        __syncthreads();
        ts[t] += x;
        __syncthreads();
    }
    if (t == 255) bsum[blockIdx.x] = ts[255];
    int run = ts[t] - s;
    if (base + 0 < n) out[base + 0] = run; run += v0;
    if (base + 1 < n) out[base + 1] = run; run += v1;
    if (base + 2 < n) out[base + 2] = run; run += v2;
    if (base + 3 < n) out[base + 3] = run;
}

__global__ void k_scan_block(const int* __restrict__ in, int* __restrict__ out, int len) {
    __shared__ int ts[256];
    int t = threadIdx.x;
    int v[8];
    int s = 0;
#pragma unroll
    for (int j = 0; j < 8; j++) {
        int i = t * 8 + j;
        v[j] = (i < len) ? in[i] : 0;
        s += v[j];
    }
    ts[t] = s;
    __syncthreads();
    for (int o = 1; o < 256; o <<= 1) {
        int x = (t >= o) ? ts[t - o] : 0;
        __syncthreads();
        ts[t] += x;
        __syncthreads();
    }
    int run = ts[t] - s;
#pragma unroll
    for (int j = 0; j < 8; j++) {
        int i = t * 8 + j;
        if (i < len) out[i] = run;
        run += v[j];
    }
}

__global__ void k_scan3(int* __restrict__ out, const int* __restrict__ bpre, int n) {
    int i = blockIdx.x * 256 + threadIdx.x;
    if (i < n) out[i] += bpre[i >> 10];
}

// -------------------- fp32 -> bf16 RTNE --------------------
__device__ __forceinline__ unsigned short f2bf(float f) {
    unsigned int b = __float_as_uint(f);
    b += 0x7fffu + ((b >> 16) & 1u);
    return (unsigned short)(b >> 16);
}

__device__ __forceinline__ void addrow8(float (&a)[8], uint4 v) {
    a[0] += __uint_as_float(v.x << 16);
    a[1] += __uint_as_float(v.x & 0xffff0000u);
    a[2] += __uint_as_float(v.y << 16);
    a[3] += __uint_as_float(v.y & 0xffff0000u);
    a[4] += __uint_as_float(v.z << 16);
    a[5] += __uint_as_float(v.z & 0xffff0000u);
    a[6] += __uint_as_float(v.w << 16);
    a[7] += __uint_as_float(v.w & 0xffff0000u);
}

// ---- layer 0 fused: gather (float4 per 4 lanes, 16 nodes/wave, 8-deep) + GEMM K=13 ----
__global__ __launch_bounds__(256) void k_gf13(const float* __restrict__ xs,
                                              const int* __restrict__ off,
                                              const int* __restrict__ indeg,
                                              const int* __restrict__ csr,
                                              const float* __restrict__ dinv,
                                              const float* __restrict__ W,
                                              const float* __restrict__ b,
                                              unsigned short* __restrict__ h, int n) {
    __shared__ float Ws[N_FEAT * HID];
    __shared__ __align__(16) float aggs[64][16];
    __shared__ float bs[HID];
    int t = threadIdx.x;
    for (int i = t; i < N_FEAT * HID; i += 256) Ws[i] = W[i];
    if (t < HID) bs[t] = b[t];
    int lane = t & 63;
    int slot = (t >> 6) * 16 + (lane >> 2);   // node slot 0..63 within block
    int l2 = lane & 3;                        // float4 index within 16-wide row
    int nb = blockIdx.x * 64;
    int d = nb + slot;
    const float4* X4 = (const float4*)xs;
    if (d < n) {
        int s0 = off[d], c = indeg[d];
        float4 acc = X4[(size_t)d * 4 + l2];   // self term (already dinv[d]-scaled)
        int p = 0;
        for (; p + 7 < c; p += 8) {            // 8 independent chains in flight
            int s_[8];
#pragma unroll
            for (int j = 0; j < 8; j++) s_[j] = csr[s0 + p + j];
            float4 v[8];
#pragma unroll
            for (int j = 0; j < 8; j++) v[j] = X4[(size_t)s_[j] * 4 + l2];
#pragma unroll
            for (int j = 0; j < 8; j++) {
                acc.x += v[j].x; acc.y += v[j].y; acc.z += v[j].z; acc.w += v[j].w;
            }
        }
        for (; p < c; p++) {
            float4 v = X4[(size_t)csr[s0 + p] * 4 + l2];
            acc.x += v.x; acc.y += v.y; acc.z += v.z; acc.w += v.w;
        }
        float dv = dinv[d];
        float4 r = {dv * acc.x, dv * acc.y, dv * acc.z, dv * acc.w};
        *(float4*)&aggs[slot][l2 * 4] = r;
    }
    __syncthreads();
    // h0 = bf16(relu(aggs @ W0 + b0)); thread owns one feature column, 32 nodes
    int f = t & 127;
    int g0 = t >> 7;                 // 0 or 1
    float wreg[N_FEAT];
#pragma unroll
    for (int k = 0; k < N_FEAT; k++) wreg[k] = Ws[k * HID + f];
#pragma unroll
    for (int j = 0; j < 32; j++) {
        int nl = g0 + j * 2;
        int dd = nb + nl;
        if (dd < n) {
            float acc = bs[f];
#pragma unroll
            for (int k = 0; k < N_FEAT; k++) acc += aggs[nl][k] * wreg[k];
            h[(size_t)dd * HID + f] = f2bf(fmaxf(acc, 0.f));
        }
    }
}

// ---------- W1,W2 (fp32 [K][N] row-major) -> Wt (bf16 [N][K]) in one launch ----------
__global__ void k_wcast2(const float* __restrict__ W1, const float* __restrict__ W2,
                         unsigned short* __restrict__ Wt1, unsigned short* __restrict__ Wt2) {
    int i = blockIdx.x * 256 + threadIdx.x;
    if (i < HID * HID) {
        int c = i >> 7, k = i & 127;
        Wt1[i] = f2bf(W1[k * HID + c]);
        Wt2[i] = f2bf(W2[k * HID + c]);
    }
}

// ---------- MFMA GEMM: ubf = bf16( dinv * (X @ W) ), X bf16 [n][128], Wt bf16 [128][128] ----------
__global__ __launch_bounds__(256) void k_mfma128(const unsigned short* __restrict__ X,
                                                 const unsigned short* __restrict__ Wt,
                                                 const float* __restrict__ dinv,
                                                 unsigned short* __restrict__ ubf, int n) {
    int t = threadIdx.x;
    int wave = t >> 6, lane = t & 63;
    int lrow = lane & 15;          // A row within tile / D col within col-tile
    int lk8 = (lane >> 4) * 8;     // k-chunk base within 32-wide K step
    int tile0 = blockIdx.x * 16 + wave * 4;   // first of 4 node-tiles for this wave

    f32x4 acc[4][8];
#pragma unroll
    for (int nt = 0; nt < 4; nt++)
#pragma unroll
        for (int ct = 0; ct < 8; ct++) acc[nt][ct] = f32x4{0.f, 0.f, 0.f, 0.f};

#pragma unroll
    for (int s = 0; s < 4; s++) {               // K steps of 32
        bf16x8 bfr[8];
#pragma unroll
        for (int ct = 0; ct < 8; ct++) {        // B frags: Wt[col][s*32+lk8 ..+8]
            int col = ct * 16 + lrow;
            bfr[ct] = *(const bf16x8*)&Wt[col * HID + s * 32 + lk8];
        }
#pragma unroll
        for (int nt = 0; nt < 4; nt++) {
            int row = min((tile0 + nt) * 16 + lrow, n - 1);
            bf16x8 afr = *(const bf16x8*)&X[(size_t)row * HID + s * 32 + lk8];
#pragma unroll
            for (int ct = 0; ct < 8; ct++)
                acc[nt][ct] = __builtin_amdgcn_mfma_f32_16x16x32_bf16(afr, bfr[ct], acc[nt][ct], 0, 0, 0);
        }
    }

    // D layout: col = lane&15 (within col-tile), row = (lane>>4)*4 + r
#pragma unroll
    for (int nt = 0; nt < 4; nt++) {
        int rbase = (tile0 + nt) * 16 + (lane >> 4) * 4;
#pragma unroll
        for (int r = 0; r < 4; r++) {
            int row = rbase + r;
            if (row < n) {
                float dv = dinv[row];
#pragma unroll
                for (int ct = 0; ct < 8; ct++)
                    ubf[(size_t)row * HID + ct * 16 + lrow] = f2bf(dv * acc[nt][ct][r]);
            }
        }
    }
}

// ---- layer-1 gather over bf16 rows: quarter-wave per dst, uint4 lanes, 8-deep ----
__global__ void k_gather128(const unsigned int* __restrict__ ubf, const int* __restrict__ off,
                            const int* __restrict__ indeg, const int* __restrict__ csr,
                            const float* __restrict__ dinv, const float* __restrict__ bias,
                            unsigned short* __restrict__ yh, int n) {
    int t = threadIdx.x;
    int lane = t & 63;
    int quad = lane >> 4, l4 = lane & 15;
    int d = blockIdx.x * 16 + (t >> 6) * 4 + quad;   // 16 nodes per 256-thread block
    if (d >= n) return;
    int s0 = off[d], c = indeg[d];
    const uint4* U = (const uint4*)ubf;   // one row = 16 uint4 (128 bf16)

    uint4 sv = U[(size_t)d * 16 + l4];    // self term
    float a[8] = {0.f, 0.f, 0.f, 0.f, 0.f, 0.f, 0.f, 0.f};
    addrow8(a, sv);

    int p = 0;
    for (; p + 7 < c; p += 8) {           // 8 rows in flight per quarter-wave
        int s_[8];
#pragma unroll
        for (int j = 0; j < 8; j++) s_[j] = csr[s0 + p + j];
        uint4 v[8];
#pragma unroll
        for (int j = 0; j < 8; j++) v[j] = U[(size_t)s_[j] * 16 + l4];
#pragma unroll
        for (int j = 0; j < 8; j++) addrow8(a, v[j]);
    }
    if (p + 3 < c) {
        int s_[4];
#pragma unroll
        for (int j = 0; j < 4; j++) s_[j] = csr[s0 + p + j];
        uint4 v[4];
#pragma unroll
        for (int j = 0; j < 4; j++) v[j] = U[(size_t)s_[j] * 16 + l4];
#pragma unroll
        for (int j = 0; j < 4; j++) addrow8(a, v[j]);
        p += 4;
    }
    for (; p < c; p++) addrow8(a, U[(size_t)csr[s0 + p] * 16 + l4]);

    float dv = dinv[d];
    float4 bb0 = *(const float4*)&bias[l4 * 8];
    float4 bb1 = *(const float4*)&bias[l4 * 8 + 4];
    float r[8];
    r[0] = dv * a[0] + bb0.x; r[1] = dv * a[1] + bb0.y;
    r[2] = dv * a[2] + bb0.z; r[3] = dv * a[3] + bb0.w;
    r[4] = dv * a[4] + bb1.x; r[5] = dv * a[5] + bb1.y;
    r[6] = dv * a[6] + bb1.z; r[7] = dv * a[7] + bb1.w;
    ushort8 hh;
#pragma unroll
    for (int j = 0; j < 8; j++) hh[j] = f2bf(fmaxf(r[j], 0.f));
    *(ushort8*)&yh[(size_t)d * HID + l4 * 8] = hh;
}

// ---- layer-2 gather (quarter-wave, uint4) fused with mean-pool accumulation ----
__global__ void k_gather128p(const unsigned int* __restrict__ ubf, const int* __restrict__ off,
                             const int* __restrict__ indeg, const int* __restrict__ csr,
                             const float* __restrict__ dinv, const float* __restrict__ bias,
                             const int* __restrict__ batch, float* __restrict__ pooledm, int n) {
    __shared__ __align__(16) float part[16][128];
    __shared__ int bid[16];
    int t = threadIdx.x;
    int lane = t & 63;
    int quad = lane >> 4, l4 = lane & 15;
    int slot = (t >> 6) * 4 + quad;           // 0..15
    int d = blockIdx.x * 16 + slot;
    const uint4* U = (const uint4*)ubf;
    if (d < n) {
        int s0 = off[d], c = indeg[d];
        uint4 sv = U[(size_t)d * 16 + l4];
        float a[8] = {0.f, 0.f, 0.f, 0.f, 0.f, 0.f, 0.f, 0.f};
        addrow8(a, sv);
        int p = 0;
        for (; p + 7 < c; p += 8) {
            int s_[8];
#pragma unroll
            for (int j = 0; j < 8; j++) s_[j] = csr[s0 + p + j];
            uint4 v[8];
#pragma unroll
            for (int j = 0; j < 8; j++) v[j] = U[(size_t)s_[j] * 16 + l4];
#pragma unroll
            for (int j = 0; j < 8; j++) addrow8(a, v[j]);
        }
        if (p + 3 < c) {
            int s_[4];
#pragma unroll
            for (int j = 0; j < 4; j++) s_[j] = csr[s0 + p + j];
            uint4 v[4];
#pragma unroll
            for (int j = 0; j < 4; j++) v[j] = U[(size_t)s_[j] * 16 + l4];
#pragma unroll
            for (int j = 0; j < 4; j++) addrow8(a, v[j]);
            p += 4;
        }
        for (; p < c; p++) addrow8(a, U[(size_t)csr[s0 + p] * 16 + l4]);

        float dv = dinv[d];
        float4 bb0 = *(const float4*)&bias[l4 * 8];
        float4 bb1 = *(const float4*)&bias[l4 * 8 + 4];
        float4 r0 = {dv * a[0] + bb0.x, dv * a[1] + bb0.y, dv * a[2] + bb0.z, dv * a[3] + bb0.w};
        float4 r1 = {dv * a[4] + bb1.x, dv * a[5] + bb1.y, dv * a[6] + bb1.z, dv * a[7] + bb1.w};
        *(float4*)&part[slot][l4 * 8] = r0;
        *(float4*)&part[slot][l4 * 8 + 4] = r1;
        if (l4 == 0) bid[slot] = batch[d];
    } else {
        if (l4 == 0) bid[slot] = -1;
    }
    __syncthreads();
    if (t < 128) {      // per-feature run reduction over the 16 nodes
        int f = t;
        float acc = 0.f;
        int g = -1;
        for (int j = 0; j < 16; j++) {
            int bj = bid[j];
            if (bj < 0) break;    // tail block: invalid nodes are trailing
            if (bj != g) {
                if (g >= 0) atomicAdd(&pooledm[g * HID + f], acc);
                g = bj; acc = 0.f;
            }
            acc += part[j][f];
        }
        if (g >= 0) atomicAdd(&pooledm[g * HID + f], acc);
    }
}

// -------------------- graph node counts --------------------
__global__ void k_cnt(const int* __restrict__ batch, int* __restrict__ cnt, int n) {
    int i = blockIdx.x * 256 + threadIdx.x;
    if (i < n) atomicAdd(&cnt[batch[i]], 1);
}

// -------------------- MLP head --------------------
__global__ void k_fc0(const float* __restrict__ in, const int* __restrict__ cnt,
                      const float* __restrict__ W, const float* __restrict__ b,
                      float* __restrict__ out) {
    __shared__ float row[128];
    int g = blockIdx.x, t = threadIdx.x;   // 256 threads
    if (t < 128) row[t] = in[g * 128 + t] * (1.f / (float)max(cnt[g], 1));
    __syncthreads();
    float acc = 0.f;
#pragma unroll 8
    for (int k = 0; k < 128; k++) acc += row[k] * W[k * 256 + t];
    acc += b[t];
    out[g * 256 + t] = fmaxf(acc, 0.f);
}

__global__ void k_fc1(const float* __restrict__ in, const float* __restrict__ W,
                      const float* __restrict__ b, float* __restrict__ out) {
    __shared__ float row[256];
    int g = blockIdx.x, t = threadIdx.x;   // 128 threads
    row[t] = in[g * 256 + t];
    row[t + 128] = in[g * 256 + t + 128];
    __syncthreads();
    float acc = 0.f;
#pragma unroll 8
    for (int k = 0; k < 256; k++) acc += row[k] * W[k * 128 + t];
    acc += b[t];
    out[g * 128 + t] = fmaxf(acc, 0.f);
}

__global__ void k_fco(const float* __restrict__ in, const float* __restrict__ Wo,
                      const float* __restrict__ bo, float* __restrict__ out) {
    int g = blockIdx.x, t = threadIdx.x;   // 64 threads = 1 wave
    float acc = in[g * 128 + t] * Wo[t] + in[g * 128 + 64 + t] * Wo[64 + t];
    for (int s = 32; s > 0; s >>= 1) acc += __shfl_down(acc, s);
    if (t == 0) out[g] = acc + bo[0];
}

// -------------------- launch --------------------
extern "C" void kernel_launch(void* const* d_in, const int* in_sizes, int n_in,
                              void* d_out, int out_size, void* d_ws, size_t ws_size,
                              hipStream_t stream) {
    const float* x   = (const float*)d_in[0];
    const int* ei    = (const int*)d_in[1];
    const int* src   = ei;
    const int* dst   = ei + N_EDGES;
    const int* batch = (const int*)d_in[2];
    const float* W0 = (const float*)d_in[3];  const float* b0 = (const float*)d_in[4];
    const float* W1 = (const float*)d_in[5];  const float* b1 = (const float*)d_in[6];
    const float* W2 = (const float*)d_in[7];  const float* b2 = (const float*)d_in[8];
    const float* Wf0 = (const float*)d_in[9];  const float* bf0 = (const float*)d_in[10];
    const float* Wf1 = (const float*)d_in[11]; const float* bf1 = (const float*)d_in[12];
    const float* Wo = (const float*)d_in[13];  const float* bo = (const float*)d_in[14];
    float* out = (float*)d_out;

    char* w = (char*)d_ws;
    size_t o = 0;
    auto take = [&](size_t bytes) -> char* {
        char* p = w + o;
        o += (bytes + 255) & ~(size_t)255;
        return p;
    };
    int* indeg    = (int*)take((size_t)N_NODES * 4);
    int* off      = (int*)take((size_t)N_NODES * 4);
    int* counts   = (int*)take((size_t)N2 * 4);
    int* countsT  = (int*)take((size_t)N2 * 4);
    int* scT      = (int*)take((size_t)N2 * 4);
    int* bsum     = (int*)take(256 * 4);
    int* bpre     = (int*)take(256 * 4);
    int* csr      = (int*)take((size_t)N_EDGES * 4);
    float* dinv   = (float*)take((size_t)N_NODES * 4);
    int* cnt      = (int*)take((size_t)N_GRAPHS * 4);
    float* xs     = (float*)take((size_t)N_NODES * 16 * 4);
    unsigned short* hbf0 = (unsigned short*)take((size_t)N_NODES * HID * 2);
    unsigned short* hbf1 = (unsigned short*)take((size_t)N_NODES * HID * 2);
    unsigned short* ubf  = (unsigned short*)take((size_t)N_NODES * HID * 2);
    unsigned short* Wt1  = (unsigned short*)take((size_t)HID * HID * 2);
    unsigned short* Wt2  = (unsigned short*)take((size_t)HID * HID * 2);
    float* pooledm= (float*)take((size_t)N_GRAPHS * HID * 4);
    float* fc0    = (float*)take((size_t)N_GRAPHS * 256 * 4);
    float* fc1    = (float*)take((size_t)N_GRAPHS * HID * 4);
    // bstore (6.4MB) aliases ubf (25.6MB): bstore dead after k_bfill; ubf written later
    unsigned int* bstore = (unsigned int*)ubf;

    hipMemsetAsync(cnt, 0, (size_t)N_GRAPHS * 4, stream);
    hipMemsetAsync(pooledm, 0, (size_t)N_GRAPHS * HID * 4, stream);

    // ---- topology: contention-free counting sort by dst bucket ----
    k_hist1<<<NBLK, 256, 0, stream>>>(dst, counts, N_EDGES);
    k_transp<<<(N2 + 255) / 256, 256, 0, stream>>>(counts, countsT);
    int nb2 = (N2 + 1023) / 1024;
    k_scan1<<<nb2, 256, 0, stream>>>(countsT, scT, bsum, N2);
    k_scan_block<<<1, 256, 0, stream>>>(bsum, bpre, nb2);
    k_scan3<<<(N2 + 255) / 256, 256, 0, stream>>>(scT, bpre, N2);
    k_scatter<<<NBLK, 256, 0, stream>>>(src, dst, scT, bstore, N_EDGES);
    k_bhistx<<<NB, 256, 0, stream>>>(bstore, scT, x, indeg, dinv, xs, N_NODES, N_EDGES);
    int nb1 = (N_NODES + 1023) / 1024;
    k_scan1<<<nb1, 256, 0, stream>>>(indeg, off, bsum, N_NODES);
    k_scan_block<<<1, 256, 0, stream>>>(bsum, bpre, nb1);
    k_scan3<<<(N_NODES + 255) / 256, 256, 0, stream>>>(off, bpre, N_NODES);
    k_bfill<<<NB, 256, 0, stream>>>(bstore, scT, off, csr, N_NODES, N_EDGES);
    k_cnt<<<(N_NODES + 255) / 256, 256, 0, stream>>>(batch, cnt, N_NODES);
    k_wcast2<<<(HID * HID + 255) / 256, 256, 0, stream>>>(W1, W2, Wt1, Wt2);

    // layer 0: fused gather(13-wide) + GEMM -> bf16 h0
    k_gf13<<<(N_NODES + 63) / 64, 256, 0, stream>>>(xs, off, indeg, csr, dinv, W0, b0, hbf0, N_NODES);
    // layer 1: MFMA GEMM + gather (bf16 out)
    k_mfma128<<<(N_NODES + 255) / 256, 256, 0, stream>>>(hbf0, Wt1, dinv, ubf, N_NODES);
    k_gather128<<<(N_NODES + 15) / 16, 256, 0, stream>>>((const unsigned int*)ubf, off, indeg, csr, dinv, b1, hbf1, N_NODES);
    // layer 2: MFMA GEMM + gather fused with mean-pool accumulation
    k_mfma128<<<(N_NODES + 255) / 256, 256, 0, stream>>>(hbf1, Wt2, dinv, ubf, N_NODES);
    k_gather128p<<<(N_NODES + 15) / 16, 256, 0, stream>>>((const unsigned int*)ubf, off, indeg, csr, dinv, b2, batch, pooledm, N_NODES);

    // MLP head (fc0 divides by per-graph count)
    k_fc0<<<N_GRAPHS, 256, 0, stream>>>(pooledm, cnt, Wf0, bf0, fc0);
    k_fc1<<<N_GRAPHS, 128, 0, stream>>>(fc0, Wf1, bf1, fc1);
    k_fco<<<N_GRAPHS, 64, 0, stream>>>(fc1, Wo, bo, out);
}